// Round 9
// baseline (133.162 us; speedup 1.0000x reference)
//
#include <hip/hip_runtime.h>

#define BB 4
#define CIN 256
#define COUT 256
#define HH 64
#define WW 64
#define KK 9
#define OC2 18
#define KTOT (CIN * KK)        // 2304 = 72 x 32-k steps; split-K halves of 36

typedef __attribute__((ext_vector_type(8))) _Float16 h8;
typedef __attribute__((ext_vector_type(4))) float f32x4;

static __device__ __forceinline__ h8 splat_pk(unsigned pk) {
    union { unsigned u[4]; h8 h; } s;
    s.u[0] = pk; s.u[1] = pk; s.u[2] = pk; s.u[3] = pk;
    return s.h;
}

// ---------------------------------------------------------------------------
// Kernel 1 (fused prework):
//   blocks 0..1023    : transpose x [B][C][H][W] f32 -> xT [B][px][256c] f16
//   blocks 1024..1311 : pack dcn_w -> bp fragments
//   blocks 1312..1347 : pack offset_w -> bow fragments (oc padded 18->32)
// ---------------------------------------------------------------------------
__global__ __launch_bounds__(256) void prework_kernel(
    const float* __restrict__ x, const float* __restrict__ ow,
    const float* __restrict__ dw,
    _Float16* __restrict__ xT, _Float16* __restrict__ bp,
    _Float16* __restrict__ bow)
{
    const int bid = blockIdx.x;
    const int t = threadIdx.x;
    if (bid < 1024) {
        const int b = bid >> 8, y = (bid >> 2) & 63, c0 = (bid & 3) * 64;
        __shared__ float tile[64][65];
#pragma unroll
        for (int r = 0; r < 16; ++r) {
            int idx = r * 256 + t;
            int c = idx >> 6, w = idx & 63;
            tile[c][w] = x[(((size_t)(b * CIN + c0 + c)) << 12) + (y << 6) + w];
        }
        __syncthreads();
        const int px = t >> 2;
#pragma unroll
        for (int half = 0; half < 2; ++half) {
            int cc = (t & 3) + half * 4;
            union { _Float16 h[8]; uint4 q; } u;
#pragma unroll
            for (int j = 0; j < 8; ++j) u.h[j] = (_Float16)tile[cc * 8 + j][px];
            size_t el = (((size_t)(b << 12)) + (y << 6) + px) * 256 + c0 + cc * 8;
            *(uint4*)&xT[el] = u.q;
        }
    } else if (bid < 1312) {
        // pack dcn_w: word wid = (T*16 + cotile)*64 + lane (T = 32-k step)
        int wid = (bid - 1024) * 256 + t;
        int T = wid >> 10;
        int r = wid & 1023;
        int cotile = r >> 6, lane = r & 63;
        int co = cotile * 16 + (lane & 15);
        int kbase = T * 32 + ((lane >> 4) & 3) * 8;
        union { _Float16 h[8]; uint4 q; } u;
#pragma unroll
        for (int j = 0; j < 8; ++j) {
            int k = kbase + j;
            int c = k & 255, kk = k >> 8;
            u.h[j] = (_Float16)dw[co * KTOT + c * KK + kk];
        }
        *(uint4*)&bp[(size_t)wid * 8] = u.q;
    } else {
        // pack offset_w (oc padded 18->32): wid = (T*2+nj)*64+lane
        int wid = (bid - 1312) * 256 + t;
        int T = wid >> 7;
        int r = wid & 127;
        int lane = r & 63;
        int oc = ((r >> 6) << 4) + (lane & 15);
        int kbase = T * 32 + ((lane >> 4) & 3) * 8;
        union { _Float16 h[8]; uint4 q; } u;
#pragma unroll
        for (int j = 0; j < 8; ++j) {
            int k = kbase + j;
            int c = k & 255, kk = k >> 8;
            u.h[j] = (oc < OC2) ? (_Float16)ow[oc * KTOT + c * KK + kk] : (_Float16)0.f;
        }
        *(uint4*)&bow[(size_t)wid * 8] = u.q;
    }
}

// ---------------------------------------------------------------------------
// Kernel 2: offset conv, ZERO-LDS barrier-free streaming MFMA. 256 blocks =
// 128 m-tiles(128px) x 2 K-halves; 512 thr = 8 waves, wave = 16px x 32co.
// A-fragment gathered direct to registers (lane: px=l&15, k-grp=l>>4);
// B direct from global (L1-shared across waves). 1-deep prefetch.
// ---------------------------------------------------------------------------
__global__ __launch_bounds__(512) void offset_mfma_kernel(
    const _Float16* __restrict__ xT, const _Float16* __restrict__ bow,
    float* __restrict__ opart)
{
    const int bid = blockIdx.x;
    const int m_blk = bid >> 1, kh = bid & 1;
    const int b = m_blk >> 5;
    const int pxbase = (m_blk & 31) * 128;
    const int tid = threadIdx.x;
    const int lane = tid & 63, wv = tid >> 6;
    const int colg = lane & 15, kg = lane >> 4;

    const int pxl = pxbase + (wv << 4) + colg;
    const int py = pxl >> 6, pxx = pxl & 63;

    const _Float16* xb = xT + ((size_t)b << 20);

    auto GLOAD = [&](int T, h8& R) {
        int kk = T >> 3;
        int ky = kk / 3, kx = kk - 3 * (kk / 3);
        int yy = py + ky - 1, xx = pxx + kx - 1;
        h8 v = {0, 0, 0, 0, 0, 0, 0, 0};
        if ((unsigned)yy < HH && (unsigned)xx < WW)
            v = *(const h8*)(xb + ((((yy << 6) + xx) << 8) + ((T & 7) << 5) + (kg << 3)));
        R = v;
    };
    auto BLOAD = [&](int T, uint4* br) {
#pragma unroll
        for (int nj = 0; nj < 2; ++nj)
            br[nj] = *(const uint4*)&bow[(size_t)(((T << 1) + nj) * 64 + lane) * 8];
    };

    f32x4 acc[2];
    { f32x4 z = {0.f, 0.f, 0.f, 0.f}; acc[0] = z; acc[1] = z; }

    const int Tb = kh * 36;
    h8 E, F;
    uint4 bA[2], bB[2];

    GLOAD(Tb, E);
    BLOAD(Tb, bA);
    for (int r = 0; r < 36; r += 2) {
        GLOAD(Tb + r + 1, F);
        BLOAD(Tb + r + 1, bB);
        {
            union { uint4 q; h8 h; } u0, u1;
            u0.q = bA[0]; u1.q = bA[1];
            acc[0] = __builtin_amdgcn_mfma_f32_16x16x32_f16(E, u0.h, acc[0], 0, 0, 0);
            acc[1] = __builtin_amdgcn_mfma_f32_16x16x32_f16(E, u1.h, acc[1], 0, 0, 0);
        }
        if (r + 2 < 36) { GLOAD(Tb + r + 2, E); BLOAD(Tb + r + 2, bA); }
        {
            union { uint4 q; h8 h; } u0, u1;
            u0.q = bB[0]; u1.q = bB[1];
            acc[0] = __builtin_amdgcn_mfma_f32_16x16x32_f16(F, u0.h, acc[0], 0, 0, 0);
            acc[1] = __builtin_amdgcn_mfma_f32_16x16x32_f16(F, u1.h, acc[1], 0, 0, 0);
        }
    }

    const int pxb = pxbase + (wv << 4) + kg * 4;
#pragma unroll
    for (int nj = 0; nj < 2; ++nj) {
        int oc = nj * 16 + colg;
        if (oc < OC2) {
            float4 o;
            o.x = acc[nj][0]; o.y = acc[nj][1];
            o.z = acc[nj][2]; o.w = acc[nj][3];
            *(float4*)&opart[(((size_t)((kh * BB + b) * OC2 + oc)) << 12) + pxb] = o;
        }
    }
}

// ---------------------------------------------------------------------------
// Kernel 3: fused bilinear-gather + MFMA implicit GEMM (fp16), v8.
// 256 blocks (64px x 256co), 512 thr = 8 waves: wm 0..3 (16px m-slice),
// wk 0..1 (K half, steps wk*36..+36). A fragments gathered DIRECT to
// registers (no A-LDS): lane l -> px = wm*16+(l&15), k-grp = l>>4. Each px
// gathered exactly once chip-wide. B staged block-wide in LDS (32 KB/round,
// double-buffered, both K-halves), shared by all waves. Epilogue: cross-wk
// LDS reduction. Dynamic LDS 73 KB.
// ---------------------------------------------------------------------------
__global__ __launch_bounds__(512, 2) void dcn_mfma_kernel(
    const _Float16* __restrict__ xT, const float* __restrict__ opart,
    const float* __restrict__ ob, const _Float16* __restrict__ bp,
    const float* __restrict__ db, float* __restrict__ out)
{
    extern __shared__ char smraw[];
    _Float16* Bsl = (_Float16*)smraw;                     // 2 bufs x 2 kh x 1024 words = 64 KB
    uint2* twp = (uint2*)(smraw + 65536);                 // 576 x 8 B bilinear weights (4 f16)
    uint2* tih = (uint2*)(smraw + 65536 + 4608);          // 576 x 8 B packed corner pix idx

    int P = blockIdx.x;
    int L = (P & 7) * 32 + (P >> 3);      // XCD swizzle: 32 consecutive tiles/XCD
    const int b = L >> 6;
    const int rowbase = (L & 63) * 64;    // one 64-px image row per block

    const int tid = threadIdx.x;
    const int lane = tid & 63;
    const int wv = tid >> 6;
    const int wm = wv & 3;                // px slice
    const int wk = wv >> 2;               // K half
    const int colg = lane & 15;           // A-row / D-col index
    const int kg = lane >> 4;             // k-group 0..3

    const int px_local = wm * 16 + colg;  // 0..63
    const int ebase = px_local * 9;

    // ---- bilinear table: 64 px x 9 taps (merge split-K offset partials + bias) ----
    const float* op0 = opart + (((size_t)(b * OC2)) << 12);
    const float* op1 = opart + (((size_t)((BB + b) * OC2)) << 12);
    for (int e = tid; e < 576; e += 512) {
        int p = e / 9, kk = e - (e / 9) * 9;
        int pxl = rowbase + p;
        int y = pxl >> 6, xx = pxl & 63;
        float dy = op0[((size_t)(2 * kk) << 12) + pxl]
                 + op1[((size_t)(2 * kk) << 12) + pxl] + ob[2 * kk];
        float dx = op0[((size_t)(2 * kk + 1) << 12) + pxl]
                 + op1[((size_t)(2 * kk + 1) << 12) + pxl] + ob[2 * kk + 1];
        int ky = kk / 3, kx = kk - 3 * (kk / 3);
        float sy = (float)(y - 1 + ky) + dy;
        float sx = (float)(xx - 1 + kx) + dx;
        float fy = floorf(sy), fx = floorf(sx);
        int y0 = (int)fy, x0 = (int)fx;
        float wy1 = sy - fy, wx1 = sx - fx;
        float wy0 = 1.f - wy1, wx0 = 1.f - wx1;
        bool vy0 = (unsigned)y0 < HH, vy1 = (unsigned)(y0 + 1) < HH;
        bool vx0 = (unsigned)x0 < WW, vx1 = (unsigned)(x0 + 1) < WW;
        _Float16 w00 = (_Float16)((vy0 && vx0) ? wy0 * wx0 : 0.f);
        _Float16 w01 = (_Float16)((vy0 && vx1) ? wy0 * wx1 : 0.f);
        _Float16 w10 = (_Float16)((vy1 && vx0) ? wy1 * wx0 : 0.f);
        _Float16 w11 = (_Float16)((vy1 && vx1) ? wy1 * wx1 : 0.f);
        union { _Float16 h[2]; unsigned u; } pk2;
        uint2 W;
        pk2.h[0] = w00; pk2.h[1] = w01; W.x = pk2.u;
        pk2.h[0] = w10; pk2.h[1] = w11; W.y = pk2.u;
        twp[e] = W;
        int y0c = min(max(y0, 0), HH - 1), y1c = min(max(y0 + 1, 0), HH - 1);
        int x0c = min(max(x0, 0), WW - 1), x1c = min(max(x0 + 1, 0), WW - 1);
        unsigned i00 = (unsigned)((y0c << 6) + x0c);
        unsigned i01 = (unsigned)((y0c << 6) + x1c);
        unsigned i10 = (unsigned)((y1c << 6) + x0c);
        unsigned i11 = (unsigned)((y1c << 6) + x1c);
        tih[e] = make_uint2(i00 | (i01 << 16), i10 | (i11 << 16));
    }
    __syncthreads();   // tables visible

    const char* xbyte = (const char*)(xT + ((size_t)b << 20));  // uniform -> SGPR

    // 4 coalesced corner loads for step T -> regs (16px x 64B contiguous/instr)
    auto AGLOAD = [&](int T, h8* C) {
        uint2 ij = tih[ebase + (T >> 3)];
        unsigned coff = (unsigned)(((T & 7) << 6) + (kg << 4));
        C[0] = *(const h8*)(xbyte + (((ij.x & 0xFFFFu) << 9) + coff));
        C[1] = *(const h8*)(xbyte + (((ij.x >> 16)     << 9) + coff));
        C[2] = *(const h8*)(xbyte + (((ij.y & 0xFFFFu) << 9) + coff));
        C[3] = *(const h8*)(xbyte + (((ij.y >> 16)     << 9) + coff));
    };
    // combine corners -> the A MFMA fragment (in register, no LDS)
    auto COMBINE = [&](int T, const h8* C) -> h8 {
        uint2 w = twp[ebase + (T >> 3)];
        unsigned w00 = (w.x & 0xFFFFu) * 0x10001u;
        unsigned w01 = (w.x >> 16)     * 0x10001u;
        unsigned w10 = (w.y & 0xFFFFu) * 0x10001u;
        unsigned w11 = (w.y >> 16)     * 0x10001u;
        h8 v = C[0] * splat_pk(w00);
        v += C[1] * splat_pk(w01);
        v += C[2] * splat_pk(w10);
        v += C[3] * splat_pk(w11);
        return v;
    };
    // B staging: 32 KB/round (16 KB per K-half), 4 words/thread
    auto BSTAGE_LOAD = [&](int r1, uint4* S) {
#pragma unroll
        for (int j = 0; j < 4; ++j) {
            int s = tid + j * 512;                 // 0..2047
            int kh2 = s >> 10;
            int T = kh2 * 36 + r1;
            size_t gw = (size_t)T * 1024 + (s & 1023);
            S[j] = *(const uint4*)&bp[gw * 8];
        }
    };
    auto BSTAGE_WRITE = [&](int bufp, const uint4* S) {
#pragma unroll
        for (int j = 0; j < 4; ++j) {
            int s = tid + j * 512;
            *(uint4*)&Bsl[((size_t)bufp * 2048 + s) * 8] = S[j];
        }
    };

    f32x4 acc[16];
#pragma unroll
    for (int i = 0; i < 16; ++i) { f32x4 z = {0.f, 0.f, 0.f, 0.f}; acc[i] = z; }

    auto MFMA16 = [&](int p, h8 v) {
        const _Float16* base = &Bsl[(size_t)(p * 2 + wk) * 1024 * 8];
        __builtin_amdgcn_s_setprio(1);
#pragma unroll
        for (int nj = 0; nj < 16; ++nj) {
            union { uint4 q; h8 h; } bb;
            bb.q = *(const uint4*)&base[(nj * 64 + lane) * 8];
            acc[nj] = __builtin_amdgcn_mfma_f32_16x16x32_f16(v, bb.h, acc[nj], 0, 0, 0);
        }
        __builtin_amdgcn_s_setprio(0);
    };

    const int Tb = wk * 36;
    h8 E[4], F[4];
    uint4 S[4];

    // prologue: stage round 0 into buf0, prefetch A(0)
    BSTAGE_LOAD(0, S);
    AGLOAD(Tb, E);
    BSTAGE_WRITE(0, S);
    __syncthreads();

    for (int r = 0; r < 36; r += 2) {
        // round r (buf0): issue next stage + A-prefetch EARLY, then compute
        BSTAGE_LOAD(r + 1, S);
        AGLOAD(Tb + r + 1, F);
        {
            h8 v = COMBINE(Tb + r, E);
            MFMA16(0, v);
        }
        BSTAGE_WRITE(1, S);       // vm-wait for S lands after the MFMAs
        __syncthreads();
        // round r+1 (buf1)
        if (r + 2 < 36) { BSTAGE_LOAD(r + 2, S); AGLOAD(Tb + r + 2, E); }
        {
            h8 v = COMBINE(Tb + r + 1, F);
            MFMA16(1, v);
        }
        if (r + 2 < 36) BSTAGE_WRITE(0, S);
        __syncthreads();
    }

    // ---- epilogue: cross-wk reduction through LDS (reuse Bsl, 64 KB) ----
    f32x4* red = (f32x4*)smraw;
    if (wk == 1) {
#pragma unroll
        for (int nj = 0; nj < 16; ++nj)
            red[(wm * 16 + nj) * 64 + lane] = acc[nj];
    }
    __syncthreads();
    if (wk == 0) {
#pragma unroll
        for (int nj = 0; nj < 16; ++nj) {
            f32x4 o2 = red[(wm * 16 + nj) * 64 + lane];
            int co = nj * 16 + colg;
            float bv = db[co];
            float* op = out + ((size_t)(b * COUT + co) << 12) + rowbase + wm * 16 + kg * 4;
            float4 st;
            st.x = acc[nj][0] + o2[0] + bv;
            st.y = acc[nj][1] + o2[1] + bv;
            st.z = acc[nj][2] + o2[2] + bv;
            st.w = acc[nj][3] + o2[3] + bv;
            *(float4*)op = st;
        }
    }
}

// ---------------------------------------------------------------------------
extern "C" void kernel_launch(void* const* d_in, const int* in_sizes, int n_in,
                              void* d_out, int out_size, void* d_ws, size_t ws_size,
                              hipStream_t stream)
{
    const float* x  = (const float*)d_in[0];
    const float* ow = (const float*)d_in[1];
    const float* ob = (const float*)d_in[2];
    const float* dw = (const float*)d_in[3];
    const float* db = (const float*)d_in[4];
    float* out = (float*)d_out;

    // ws layout (bytes):
    // opart f32 [2][4][18][4096] = 2359296 | bp f16 1179648 | bow f16 147456 | xT f16 8388608
    char* wsp = (char*)d_ws;
    float*     opart = (float*)wsp;
    _Float16*  bp    = (_Float16*)(wsp + 2359296);
    _Float16*  bow   = (_Float16*)(wsp + 3538944);
    _Float16*  xT    = (_Float16*)(wsp + 3686400);

    const int DYN_LDS = 65536 + 4608 + 4608;   // Bsl + twp + tih = 74752 B

    hipFuncSetAttribute((const void*)dcn_mfma_kernel,
                        hipFuncAttributeMaxDynamicSharedMemorySize, DYN_LDS);

    hipLaunchKernelGGL(prework_kernel,     dim3(1348), dim3(256), 0, stream, x, ow, dw, xT, bp, bow);
    hipLaunchKernelGGL(offset_mfma_kernel, dim3(256),  dim3(512), 0, stream, xT, bow, opart);
    hipLaunchKernelGGL(dcn_mfma_kernel,    dim3(256),  dim3(512), DYN_LDS, stream,
                       xT, opart, ob, bp, db, out);
}

// Round 10
// 71.452 us; speedup vs baseline: 1.8636x; 1.8636x over previous
//
#include <hip/hip_runtime.h>

#define BB 4
#define CIN 256
#define COUT 256
#define HH 64
#define WW 64
#define KK 9
#define OC2 18
#define KTOT (CIN * KK)        // 2304 = 72 x 32-k steps = 18 x 128-k stages

typedef __attribute__((ext_vector_type(8))) _Float16 h8;
typedef __attribute__((ext_vector_type(4))) float f32x4;

static __device__ __forceinline__ h8 splat_pk(unsigned pk) {
    union { unsigned u[4]; h8 h; } s;
    s.u[0] = pk; s.u[1] = pk; s.u[2] = pk; s.u[3] = pk;
    return s.h;
}

// ---------------------------------------------------------------------------
// Kernel 1 (fused prework):
//   blocks 0..1023    : transpose x [B][C][H][W] f32 -> xT [B][px][256c] f16
//   blocks 1024..1311 : pack dcn_w -> bp fragments
//   blocks 1312..1347 : pack offset_w -> bow fragments (oc padded 18->32)
// ---------------------------------------------------------------------------
__global__ __launch_bounds__(256) void prework_kernel(
    const float* __restrict__ x, const float* __restrict__ ow,
    const float* __restrict__ dw,
    _Float16* __restrict__ xT, _Float16* __restrict__ bp,
    _Float16* __restrict__ bow)
{
    const int bid = blockIdx.x;
    const int t = threadIdx.x;
    if (bid < 1024) {
        const int b = bid >> 8, y = (bid >> 2) & 63, c0 = (bid & 3) * 64;
        __shared__ float tile[64][65];
#pragma unroll
        for (int r = 0; r < 16; ++r) {
            int idx = r * 256 + t;
            int c = idx >> 6, w = idx & 63;
            tile[c][w] = x[(((size_t)(b * CIN + c0 + c)) << 12) + (y << 6) + w];
        }
        __syncthreads();
        const int px = t >> 2;
#pragma unroll
        for (int half = 0; half < 2; ++half) {
            int cc = (t & 3) + half * 4;
            union { _Float16 h[8]; uint4 q; } u;
#pragma unroll
            for (int j = 0; j < 8; ++j) u.h[j] = (_Float16)tile[cc * 8 + j][px];
            size_t el = (((size_t)(b << 12)) + (y << 6) + px) * 256 + c0 + cc * 8;
            *(uint4*)&xT[el] = u.q;
        }
    } else if (bid < 1312) {
        // pack dcn_w: word wid = (T*16 + cotile)*64 + lane (T = 32-k step)
        int wid = (bid - 1024) * 256 + t;
        int T = wid >> 10;
        int r = wid & 1023;
        int cotile = r >> 6, lane = r & 63;
        int co = cotile * 16 + (lane & 15);
        int kbase = T * 32 + ((lane >> 4) & 3) * 8;
        union { _Float16 h[8]; uint4 q; } u;
#pragma unroll
        for (int j = 0; j < 8; ++j) {
            int k = kbase + j;
            int c = k & 255, kk = k >> 8;
            u.h[j] = (_Float16)dw[co * KTOT + c * KK + kk];
        }
        *(uint4*)&bp[(size_t)wid * 8] = u.q;
    } else {
        // pack offset_w (oc padded 18->32): wid = (T*2+nj)*64+lane
        int wid = (bid - 1312) * 256 + t;
        int T = wid >> 7;
        int r = wid & 127;
        int lane = r & 63;
        int oc = ((r >> 6) << 4) + (lane & 15);
        int kbase = T * 32 + ((lane >> 4) & 3) * 8;
        union { _Float16 h[8]; uint4 q; } u;
#pragma unroll
        for (int j = 0; j < 8; ++j) {
            int k = kbase + j;
            int c = k & 255, kk = k >> 8;
            u.h[j] = (oc < OC2) ? (_Float16)ow[oc * KTOT + c * KK + kk] : (_Float16)0.f;
        }
        *(uint4*)&bow[(size_t)wid * 8] = u.q;
    }
}

// ---------------------------------------------------------------------------
// Kernel 2: offset conv, ZERO-LDS barrier-free streaming MFMA. 256 blocks =
// 128 m-tiles(128px) x 2 K-halves; 512 thr = 8 waves, wave = 16px x 32co.
// ---------------------------------------------------------------------------
__global__ __launch_bounds__(512) void offset_mfma_kernel(
    const _Float16* __restrict__ xT, const _Float16* __restrict__ bow,
    float* __restrict__ opart)
{
    const int bid = blockIdx.x;
    const int m_blk = bid >> 1, kh = bid & 1;
    const int b = m_blk >> 5;
    const int pxbase = (m_blk & 31) * 128;
    const int tid = threadIdx.x;
    const int lane = tid & 63, wv = tid >> 6;
    const int colg = lane & 15, kg = lane >> 4;

    const int pxl = pxbase + (wv << 4) + colg;
    const int py = pxl >> 6, pxx = pxl & 63;

    const _Float16* xb = xT + ((size_t)b << 20);

    auto GLOAD = [&](int T, h8& R) {
        int kk = T >> 3;
        int ky = kk / 3, kx = kk - 3 * (kk / 3);
        int yy = py + ky - 1, xx = pxx + kx - 1;
        h8 v = {0, 0, 0, 0, 0, 0, 0, 0};
        if ((unsigned)yy < HH && (unsigned)xx < WW)
            v = *(const h8*)(xb + ((((yy << 6) + xx) << 8) + ((T & 7) << 5) + (kg << 3)));
        R = v;
    };
    auto BLOAD = [&](int T, uint4* br) {
#pragma unroll
        for (int nj = 0; nj < 2; ++nj)
            br[nj] = *(const uint4*)&bow[(size_t)(((T << 1) + nj) * 64 + lane) * 8];
    };

    f32x4 acc[2];
    { f32x4 z = {0.f, 0.f, 0.f, 0.f}; acc[0] = z; acc[1] = z; }

    const int Tb = kh * 36;
    h8 E, F;
    uint4 bA[2], bB[2];

    GLOAD(Tb, E);
    BLOAD(Tb, bA);
    for (int r = 0; r < 36; r += 2) {
        GLOAD(Tb + r + 1, F);
        BLOAD(Tb + r + 1, bB);
        {
            union { uint4 q; h8 h; } u0, u1;
            u0.q = bA[0]; u1.q = bA[1];
            acc[0] = __builtin_amdgcn_mfma_f32_16x16x32_f16(E, u0.h, acc[0], 0, 0, 0);
            acc[1] = __builtin_amdgcn_mfma_f32_16x16x32_f16(E, u1.h, acc[1], 0, 0, 0);
        }
        if (r + 2 < 36) { GLOAD(Tb + r + 2, E); BLOAD(Tb + r + 2, bA); }
        {
            union { uint4 q; h8 h; } u0, u1;
            u0.q = bB[0]; u1.q = bB[1];
            acc[0] = __builtin_amdgcn_mfma_f32_16x16x32_f16(F, u0.h, acc[0], 0, 0, 0);
            acc[1] = __builtin_amdgcn_mfma_f32_16x16x32_f16(F, u1.h, acc[1], 0, 0, 0);
        }
    }

    const int pxb = pxbase + (wv << 4) + kg * 4;
#pragma unroll
    for (int nj = 0; nj < 2; ++nj) {
        int oc = nj * 16 + colg;
        if (oc < OC2) {
            float4 o;
            o.x = acc[nj][0]; o.y = acc[nj][1];
            o.z = acc[nj][2]; o.w = acc[nj][3];
            *(float4*)&opart[(((size_t)((kh * BB + b) * OC2 + oc)) << 12) + pxb] = o;
        }
    }
}

// ---------------------------------------------------------------------------
// Kernel 3: fused bilinear-gather + MFMA implicit GEMM (fp16), v10.
// 512 blocks (64px x 128co) = 2/CU. 512 thr = 8 waves = 8 N-SLICES:
// wave = 64px x 16co (4 m-frags, acc=16 VGPR), all 72 32-k steps.
// A: gathered ONCE per block to LDS (2 words/thread per 128k stage),
//    double-buffered, pad-17 word layout (conflict-free write AND read).
// B: global -> registers, each wave loads only its own co-slice
//    (B read exactly once per block - no LDS, no redundancy).
// Per wave-stage: 8 corner loads + 4 B loads + 16 ds_read + 16 MFMA.
// ---------------------------------------------------------------------------
__global__ __launch_bounds__(512, 2) void dcn_mfma_kernel(
    const _Float16* __restrict__ xT, const float* __restrict__ opart,
    const float* __restrict__ ob, const _Float16* __restrict__ bp,
    const float* __restrict__ db, float* __restrict__ out)
{
    __shared__ __align__(16) _Float16 Asl[2][1088 * 8];  // pad-17: 17.4 KB/buf
    __shared__ __align__(8) uint2 twp[576];              // packed bilinear wgts
    __shared__ __align__(8) uint2 tih[576];              // packed corner px idx

    int P = blockIdx.x;
    int L = (P & 7) * 64 + (P >> 3);      // XCD swizzle (512 % 8 == 0)
    const int m_blk = L >> 1, n0 = L & 1;
    const int b = m_blk >> 6;
    const int rowbase = (m_blk & 63) * 64;   // one 64-px image row

    const int tid = threadIdx.x;
    const int lane = tid & 63;
    const int wn = tid >> 6;              // 0..7 = co slice (16 co)
    const int colg = lane & 15, kg = lane >> 4;

    // gather role: thread stages words (g_px, g_cgp) and (g_px, g_cgp+8)
    const int g_px = tid >> 3;            // 0..63
    const int g_cgp = tid & 7;            // 0..7
    const int g_ebase = g_px * 9;
    const int g_w0 = g_px * 17 + g_cgp;   // pad-17 word index (+8 for 2nd)

    // ---- bilinear table: 64 px x 9 taps (merge split-K partials + bias) ----
    const float* op0 = opart + (((size_t)(b * OC2)) << 12);
    const float* op1 = opart + (((size_t)((BB + b) * OC2)) << 12);
    for (int e = tid; e < 576; e += 512) {
        int p = e / 9, kk = e - (e / 9) * 9;
        int pxl = rowbase + p;
        int y = pxl >> 6, xx = pxl & 63;
        float dy = op0[((size_t)(2 * kk) << 12) + pxl]
                 + op1[((size_t)(2 * kk) << 12) + pxl] + ob[2 * kk];
        float dx = op0[((size_t)(2 * kk + 1) << 12) + pxl]
                 + op1[((size_t)(2 * kk + 1) << 12) + pxl] + ob[2 * kk + 1];
        int ky = kk / 3, kx = kk - 3 * (kk / 3);
        float sy = (float)(y - 1 + ky) + dy;
        float sx = (float)(xx - 1 + kx) + dx;
        float fy = floorf(sy), fx = floorf(sx);
        int y0 = (int)fy, x0 = (int)fx;
        float wy1 = sy - fy, wx1 = sx - fx;
        float wy0 = 1.f - wy1, wx0 = 1.f - wx1;
        bool vy0 = (unsigned)y0 < HH, vy1 = (unsigned)(y0 + 1) < HH;
        bool vx0 = (unsigned)x0 < WW, vx1 = (unsigned)(x0 + 1) < WW;
        _Float16 w00 = (_Float16)((vy0 && vx0) ? wy0 * wx0 : 0.f);
        _Float16 w01 = (_Float16)((vy0 && vx1) ? wy0 * wx1 : 0.f);
        _Float16 w10 = (_Float16)((vy1 && vx0) ? wy1 * wx0 : 0.f);
        _Float16 w11 = (_Float16)((vy1 && vx1) ? wy1 * wx1 : 0.f);
        union { _Float16 h[2]; unsigned u; } pk2;
        uint2 W;
        pk2.h[0] = w00; pk2.h[1] = w01; W.x = pk2.u;
        pk2.h[0] = w10; pk2.h[1] = w11; W.y = pk2.u;
        twp[e] = W;
        int y0c = min(max(y0, 0), HH - 1), y1c = min(max(y0 + 1, 0), HH - 1);
        int x0c = min(max(x0, 0), WW - 1), x1c = min(max(x0 + 1, 0), WW - 1);
        unsigned i00 = (unsigned)((y0c << 6) + x0c);
        unsigned i01 = (unsigned)((y0c << 6) + x1c);
        unsigned i10 = (unsigned)((y1c << 6) + x0c);
        unsigned i11 = (unsigned)((y1c << 6) + x1c);
        tih[e] = make_uint2(i00 | (i01 << 16), i10 | (i11 << 16));
    }
    __syncthreads();

    const char* xbyte = (const char*)(xT + ((size_t)b << 20));  // uniform

    // 8 coalesced corner loads for stage st: 4 corners x 2 cg-words
    auto AGLOAD = [&](int st, h8* C) {
        uint2 ij = tih[g_ebase + (st >> 1)];
        unsigned chb = (unsigned)((st & 1) * 256 + g_cgp * 16);
        const char* p0 = xbyte + (((ij.x & 0xFFFFu) << 9) + chb);
        const char* p1 = xbyte + (((ij.x >> 16)     << 9) + chb);
        const char* p2 = xbyte + (((ij.y & 0xFFFFu) << 9) + chb);
        const char* p3 = xbyte + (((ij.y >> 16)     << 9) + chb);
        C[0] = *(const h8*)p0;         C[4] = *(const h8*)(p0 + 128);
        C[1] = *(const h8*)p1;         C[5] = *(const h8*)(p1 + 128);
        C[2] = *(const h8*)p2;         C[6] = *(const h8*)(p2 + 128);
        C[3] = *(const h8*)p3;         C[7] = *(const h8*)(p3 + 128);
    };
    // combine + 2 ds_writes (vm-wait for C lands here, after the MFMAs)
    auto GCONSUME = [&](int st, int buf, const h8* C) {
        uint2 w = twp[g_ebase + (st >> 1)];
        unsigned w00 = (w.x & 0xFFFFu) * 0x10001u;
        unsigned w01 = (w.x >> 16)     * 0x10001u;
        unsigned w10 = (w.y & 0xFFFFu) * 0x10001u;
        unsigned w11 = (w.y >> 16)     * 0x10001u;
        h8 s00 = splat_pk(w00), s01 = splat_pk(w01);
        h8 s10 = splat_pk(w10), s11 = splat_pk(w11);
        h8 v0 = C[0] * s00; v0 += C[1] * s01; v0 += C[2] * s10; v0 += C[3] * s11;
        h8 v1 = C[4] * s00; v1 += C[5] * s01; v1 += C[6] * s10; v1 += C[7] * s11;
        *(h8*)&Asl[buf][g_w0 * 8] = v0;
        *(h8*)&Asl[buf][(g_w0 + 8) * 8] = v1;
    };
    // B: 4 words per wave per stage (its own 16-co slice only)
    auto BLOAD = [&](int st, uint4* br) {
#pragma unroll
        for (int ks = 0; ks < 4; ++ks) {
            size_t word = ((size_t)((st * 4 + ks) * 16 + n0 * 8 + wn)) * 64 + lane;
            br[ks] = *(const uint4*)&bp[word * 8];
        }
    };

    f32x4 acc[4];
#pragma unroll
    for (int i = 0; i < 4; ++i) { f32x4 z = {0.f, 0.f, 0.f, 0.f}; acc[i] = z; }

    const int rdbase = colg * 17 + kg;    // lane part of read index
    auto MFMA16 = [&](int buf, uint4* br) {
        __builtin_amdgcn_s_setprio(1);
#pragma unroll
        for (int ks = 0; ks < 4; ++ks) {
            union { uint4 q; h8 h; } bb; bb.q = br[ks];
#pragma unroll
            for (int mi = 0; mi < 4; ++mi) {
                h8 a = *(const h8*)&Asl[buf][(mi * 272 + ks * 4 + rdbase) * 8];
                acc[mi] = __builtin_amdgcn_mfma_f32_16x16x32_f16(a, bb.h, acc[mi], 0, 0, 0);
            }
        }
        __builtin_amdgcn_s_setprio(0);
    };

    h8 C[8];
    uint4 breg[4], bnext[4];

    AGLOAD(0, C);
    BLOAD(0, breg);
    GCONSUME(0, 0, C);
    __syncthreads();

    for (int s = 0; s < 18; ++s) {
        const int cur = s & 1;
        if (s + 1 < 18) {
            BLOAD(s + 1, bnext);          // B prefetch in flight over MFMAs
            AGLOAD(s + 1, C);             // corner prefetch in flight
        }
        MFMA16(cur, breg);
        if (s + 1 < 18) GCONSUME(s + 1, cur ^ 1, C);
        __syncthreads();
#pragma unroll
        for (int i = 0; i < 4; ++i) breg[i] = bnext[i];
    }

    // ---- epilogue: col=lane&15 -> co, row=(lane>>4)*4+reg -> px ----
    const int co = n0 * 128 + wn * 16 + colg;
    const float bv = db[co];
    float* op = out + ((size_t)(b * COUT + co) << 12) + rowbase + kg * 4;
#pragma unroll
    for (int mi = 0; mi < 4; ++mi) {
        float4 o;
        o.x = acc[mi][0] + bv;
        o.y = acc[mi][1] + bv;
        o.z = acc[mi][2] + bv;
        o.w = acc[mi][3] + bv;
        *(float4*)&op[mi * 16] = o;
    }
}

// ---------------------------------------------------------------------------
extern "C" void kernel_launch(void* const* d_in, const int* in_sizes, int n_in,
                              void* d_out, int out_size, void* d_ws, size_t ws_size,
                              hipStream_t stream)
{
    const float* x  = (const float*)d_in[0];
    const float* ow = (const float*)d_in[1];
    const float* ob = (const float*)d_in[2];
    const float* dw = (const float*)d_in[3];
    const float* db = (const float*)d_in[4];
    float* out = (float*)d_out;

    // ws layout (bytes):
    // opart f32 [2][4][18][4096] = 2359296 | bp f16 1179648 | bow f16 147456 | xT f16 8388608
    char* wsp = (char*)d_ws;
    float*     opart = (float*)wsp;
    _Float16*  bp    = (_Float16*)(wsp + 2359296);
    _Float16*  bow   = (_Float16*)(wsp + 3538944);
    _Float16*  xT    = (_Float16*)(wsp + 3686400);

    hipLaunchKernelGGL(prework_kernel,     dim3(1348), dim3(256), 0, stream, x, ow, dw, xT, bp, bow);
    hipLaunchKernelGGL(offset_mfma_kernel, dim3(256),  dim3(512), 0, stream, xT, bow, opart);
    hipLaunchKernelGGL(dcn_mfma_kernel,    dim3(512),  dim3(512), 0, stream, xT, opart, ob, bp, db, out);
}

// Round 11
// 71.243 us; speedup vs baseline: 1.8691x; 1.0029x over previous
//
#include <hip/hip_runtime.h>

#define BB 4
#define CIN 256
#define COUT 256
#define HH 64
#define WW 64
#define KK 9
#define OC2 18
#define KTOT (CIN * KK)        // 2304 = 72 x 32-k steps = 18 x 128-k stages

typedef __attribute__((ext_vector_type(8))) _Float16 h8;
typedef __attribute__((ext_vector_type(4))) float f32x4;

static __device__ __forceinline__ h8 splat_pk(unsigned pk) {
    union { unsigned u[4]; h8 h; } s;
    s.u[0] = pk; s.u[1] = pk; s.u[2] = pk; s.u[3] = pk;
    return s.h;
}

// ---------------------------------------------------------------------------
// Kernel 1 (fused prework):
//   blocks 0..1023    : transpose x [B][C][H][W] f32 -> xT [B][px][256c] f16
//   blocks 1024..1311 : pack dcn_w -> bp fragments
//   blocks 1312..1347 : pack offset_w -> bow fragments (oc padded 18->32)
// ---------------------------------------------------------------------------
__global__ __launch_bounds__(256) void prework_kernel(
    const float* __restrict__ x, const float* __restrict__ ow,
    const float* __restrict__ dw,
    _Float16* __restrict__ xT, _Float16* __restrict__ bp,
    _Float16* __restrict__ bow)
{
    const int bid = blockIdx.x;
    const int t = threadIdx.x;
    if (bid < 1024) {
        const int b = bid >> 8, y = (bid >> 2) & 63, c0 = (bid & 3) * 64;
        __shared__ float tile[64][65];
#pragma unroll
        for (int r = 0; r < 16; ++r) {
            int idx = r * 256 + t;
            int c = idx >> 6, w = idx & 63;
            tile[c][w] = x[(((size_t)(b * CIN + c0 + c)) << 12) + (y << 6) + w];
        }
        __syncthreads();
        const int px = t >> 2;
#pragma unroll
        for (int half = 0; half < 2; ++half) {
            int cc = (t & 3) + half * 4;
            union { _Float16 h[8]; uint4 q; } u;
#pragma unroll
            for (int j = 0; j < 8; ++j) u.h[j] = (_Float16)tile[cc * 8 + j][px];
            size_t el = (((size_t)(b << 12)) + (y << 6) + px) * 256 + c0 + cc * 8;
            *(uint4*)&xT[el] = u.q;
        }
    } else if (bid < 1312) {
        // pack dcn_w: word wid = (T*16 + cotile)*64 + lane (T = 32-k step)
        int wid = (bid - 1024) * 256 + t;
        int T = wid >> 10;
        int r = wid & 1023;
        int cotile = r >> 6, lane = r & 63;
        int co = cotile * 16 + (lane & 15);
        int kbase = T * 32 + ((lane >> 4) & 3) * 8;
        union { _Float16 h[8]; uint4 q; } u;
#pragma unroll
        for (int j = 0; j < 8; ++j) {
            int k = kbase + j;
            int c = k & 255, kk = k >> 8;
            u.h[j] = (_Float16)dw[co * KTOT + c * KK + kk];
        }
        *(uint4*)&bp[(size_t)wid * 8] = u.q;
    } else {
        // pack offset_w (oc padded 18->32): wid = (T*2+nj)*64+lane
        int wid = (bid - 1312) * 256 + t;
        int T = wid >> 7;
        int r = wid & 127;
        int lane = r & 63;
        int oc = ((r >> 6) << 4) + (lane & 15);
        int kbase = T * 32 + ((lane >> 4) & 3) * 8;
        union { _Float16 h[8]; uint4 q; } u;
#pragma unroll
        for (int j = 0; j < 8; ++j) {
            int k = kbase + j;
            int c = k & 255, kk = k >> 8;
            u.h[j] = (oc < OC2) ? (_Float16)ow[oc * KTOT + c * KK + kk] : (_Float16)0.f;
        }
        *(uint4*)&bow[(size_t)wid * 8] = u.q;
    }
}

// ---------------------------------------------------------------------------
// Kernel 2: offset conv, ZERO-LDS barrier-free streaming MFMA. 256 blocks =
// 128 m-tiles(128px) x 2 K-halves; 512 thr = 8 waves, wave = 16px x 32co.
// ---------------------------------------------------------------------------
__global__ __launch_bounds__(512) void offset_mfma_kernel(
    const _Float16* __restrict__ xT, const _Float16* __restrict__ bow,
    float* __restrict__ opart)
{
    const int bid = blockIdx.x;
    const int m_blk = bid >> 1, kh = bid & 1;
    const int b = m_blk >> 5;
    const int pxbase = (m_blk & 31) * 128;
    const int tid = threadIdx.x;
    const int lane = tid & 63, wv = tid >> 6;
    const int colg = lane & 15, kg = lane >> 4;

    const int pxl = pxbase + (wv << 4) + colg;
    const int py = pxl >> 6, pxx = pxl & 63;

    const _Float16* xb = xT + ((size_t)b << 20);

    auto GLOAD = [&](int T, h8& R) {
        int kk = T >> 3;
        int ky = kk / 3, kx = kk - 3 * (kk / 3);
        int yy = py + ky - 1, xx = pxx + kx - 1;
        h8 v = {0, 0, 0, 0, 0, 0, 0, 0};
        if ((unsigned)yy < HH && (unsigned)xx < WW)
            v = *(const h8*)(xb + ((((yy << 6) + xx) << 8) + ((T & 7) << 5) + (kg << 3)));
        R = v;
    };
    auto BLOAD = [&](int T, uint4* br) {
#pragma unroll
        for (int nj = 0; nj < 2; ++nj)
            br[nj] = *(const uint4*)&bow[(size_t)(((T << 1) + nj) * 64 + lane) * 8];
    };

    f32x4 acc[2];
    { f32x4 z = {0.f, 0.f, 0.f, 0.f}; acc[0] = z; acc[1] = z; }

    const int Tb = kh * 36;
    h8 E, F;
    uint4 bA[2], bB[2];

    GLOAD(Tb, E);
    BLOAD(Tb, bA);
    for (int r = 0; r < 36; r += 2) {
        GLOAD(Tb + r + 1, F);
        BLOAD(Tb + r + 1, bB);
        {
            union { uint4 q; h8 h; } u0, u1;
            u0.q = bA[0]; u1.q = bA[1];
            acc[0] = __builtin_amdgcn_mfma_f32_16x16x32_f16(E, u0.h, acc[0], 0, 0, 0);
            acc[1] = __builtin_amdgcn_mfma_f32_16x16x32_f16(E, u1.h, acc[1], 0, 0, 0);
        }
        if (r + 2 < 36) { GLOAD(Tb + r + 2, E); BLOAD(Tb + r + 2, bA); }
        {
            union { uint4 q; h8 h; } u0, u1;
            u0.q = bB[0]; u1.q = bB[1];
            acc[0] = __builtin_amdgcn_mfma_f32_16x16x32_f16(F, u0.h, acc[0], 0, 0, 0);
            acc[1] = __builtin_amdgcn_mfma_f32_16x16x32_f16(F, u1.h, acc[1], 0, 0, 0);
        }
    }

    const int pxb = pxbase + (wv << 4) + kg * 4;
#pragma unroll
    for (int nj = 0; nj < 2; ++nj) {
        int oc = nj * 16 + colg;
        if (oc < OC2) {
            float4 o;
            o.x = acc[nj][0]; o.y = acc[nj][1];
            o.z = acc[nj][2]; o.w = acc[nj][3];
            *(float4*)&opart[(((size_t)((kh * BB + b) * OC2 + oc)) << 12) + pxb] = o;
        }
    }
}

// ---------------------------------------------------------------------------
// Kernel 3: fused bilinear-gather + MFMA implicit GEMM (fp16), v11.
// 256 blocks (64px x 256co) = 1/CU: every pixel gathered ONCE chip-wide.
// 512 thr = 8 waves = 8 N-SLICES (wave = 64px x 32co: 4 m-frags x 2 n-frags,
// 16 A-reads -> 32 MFMA per stage). A in LDS, conflict-free XOR layout
// word = cg*64 + (px ^ (cg&7)); B global -> regs (each wave its own slice,
// B read once per block). Double-buffered, 1-stage prefetch on A and B.
// ---------------------------------------------------------------------------
__global__ __launch_bounds__(512, 2) void dcn_mfma_kernel(
    const _Float16* __restrict__ xT, const float* __restrict__ opart,
    const float* __restrict__ ob, const _Float16* __restrict__ bp,
    const float* __restrict__ db, float* __restrict__ out)
{
    __shared__ __align__(16) _Float16 Asl[2][1024 * 8];  // 16 KB per buf
    __shared__ __align__(8) uint2 twp[576];              // packed bilinear wgts
    __shared__ __align__(8) uint2 tih[576];              // packed corner px idx

    int P = blockIdx.x;
    int L = (P & 7) * 32 + (P >> 3);      // XCD swizzle (256 % 8 == 0)
    const int b = L >> 6;
    const int rowbase = (L & 63) * 64;    // one 64-px image row per block

    const int tid = threadIdx.x;
    const int lane = tid & 63;
    const int wn = tid >> 6;              // 0..7 = co slice (32 co)
    const int colg = lane & 15, kg = lane >> 4;

    // gather role: thread stages words (g_px, g_cgp) and (g_px, g_cgp+8)
    const int g_px = tid >> 3;            // 0..63
    const int g_cgp = tid & 7;            // 0..7
    const int g_ebase = g_px * 9;
    // XOR layout: word(cg, px) = cg*64 + (px ^ (cg&7)); (cgp+8)&7 == cgp
    const int g_w0 = g_cgp * 64 + (g_px ^ g_cgp);
    const int g_w1 = (g_cgp + 8) * 64 + (g_px ^ g_cgp);

    // ---- bilinear table: 64 px x 9 taps (merge split-K partials + bias) ----
    const float* op0 = opart + (((size_t)(b * OC2)) << 12);
    const float* op1 = opart + (((size_t)((BB + b) * OC2)) << 12);
    for (int e = tid; e < 576; e += 512) {
        int p = e / 9, kk = e - (e / 9) * 9;
        int pxl = rowbase + p;
        int y = pxl >> 6, xx = pxl & 63;
        float dy = op0[((size_t)(2 * kk) << 12) + pxl]
                 + op1[((size_t)(2 * kk) << 12) + pxl] + ob[2 * kk];
        float dx = op0[((size_t)(2 * kk + 1) << 12) + pxl]
                 + op1[((size_t)(2 * kk + 1) << 12) + pxl] + ob[2 * kk + 1];
        int ky = kk / 3, kx = kk - 3 * (kk / 3);
        float sy = (float)(y - 1 + ky) + dy;
        float sx = (float)(xx - 1 + kx) + dx;
        float fy = floorf(sy), fx = floorf(sx);
        int y0 = (int)fy, x0 = (int)fx;
        float wy1 = sy - fy, wx1 = sx - fx;
        float wy0 = 1.f - wy1, wx0 = 1.f - wx1;
        bool vy0 = (unsigned)y0 < HH, vy1 = (unsigned)(y0 + 1) < HH;
        bool vx0 = (unsigned)x0 < WW, vx1 = (unsigned)(x0 + 1) < WW;
        _Float16 w00 = (_Float16)((vy0 && vx0) ? wy0 * wx0 : 0.f);
        _Float16 w01 = (_Float16)((vy0 && vx1) ? wy0 * wx1 : 0.f);
        _Float16 w10 = (_Float16)((vy1 && vx0) ? wy1 * wx0 : 0.f);
        _Float16 w11 = (_Float16)((vy1 && vx1) ? wy1 * wx1 : 0.f);
        union { _Float16 h[2]; unsigned u; } pk2;
        uint2 W;
        pk2.h[0] = w00; pk2.h[1] = w01; W.x = pk2.u;
        pk2.h[0] = w10; pk2.h[1] = w11; W.y = pk2.u;
        twp[e] = W;
        int y0c = min(max(y0, 0), HH - 1), y1c = min(max(y0 + 1, 0), HH - 1);
        int x0c = min(max(x0, 0), WW - 1), x1c = min(max(x0 + 1, 0), WW - 1);
        unsigned i00 = (unsigned)((y0c << 6) + x0c);
        unsigned i01 = (unsigned)((y0c << 6) + x1c);
        unsigned i10 = (unsigned)((y1c << 6) + x0c);
        unsigned i11 = (unsigned)((y1c << 6) + x1c);
        tih[e] = make_uint2(i00 | (i01 << 16), i10 | (i11 << 16));
    }
    __syncthreads();

    const char* xbyte = (const char*)(xT + ((size_t)b << 20));  // uniform

    // 8 coalesced corner loads for stage st: 4 corners x 2 cg-words
    auto AGLOAD = [&](int st, h8* C) {
        uint2 ij = tih[g_ebase + (st >> 1)];
        unsigned chb = (unsigned)((st & 1) * 256 + g_cgp * 16);
        const char* p0 = xbyte + (((ij.x & 0xFFFFu) << 9) + chb);
        const char* p1 = xbyte + (((ij.x >> 16)     << 9) + chb);
        const char* p2 = xbyte + (((ij.y & 0xFFFFu) << 9) + chb);
        const char* p3 = xbyte + (((ij.y >> 16)     << 9) + chb);
        C[0] = *(const h8*)p0;         C[4] = *(const h8*)(p0 + 128);
        C[1] = *(const h8*)p1;         C[5] = *(const h8*)(p1 + 128);
        C[2] = *(const h8*)p2;         C[6] = *(const h8*)(p2 + 128);
        C[3] = *(const h8*)p3;         C[7] = *(const h8*)(p3 + 128);
    };
    // combine + 2 ds_writes (vm-wait for C lands here, after the MFMAs)
    auto GCONSUME = [&](int st, int buf, const h8* C) {
        uint2 w = twp[g_ebase + (st >> 1)];
        unsigned w00 = (w.x & 0xFFFFu) * 0x10001u;
        unsigned w01 = (w.x >> 16)     * 0x10001u;
        unsigned w10 = (w.y & 0xFFFFu) * 0x10001u;
        unsigned w11 = (w.y >> 16)     * 0x10001u;
        h8 s00 = splat_pk(w00), s01 = splat_pk(w01);
        h8 s10 = splat_pk(w10), s11 = splat_pk(w11);
        h8 v0 = C[0] * s00; v0 += C[1] * s01; v0 += C[2] * s10; v0 += C[3] * s11;
        h8 v1 = C[4] * s00; v1 += C[5] * s01; v1 += C[6] * s10; v1 += C[7] * s11;
        *(h8*)&Asl[buf][g_w0 * 8] = v0;
        *(h8*)&Asl[buf][g_w1 * 8] = v1;
    };
    // B: 8 words per wave per stage (4 ks x 2 nj), own 32-co slice only
    auto BLOAD = [&](int st, uint4* br) {
#pragma unroll
        for (int ks = 0; ks < 4; ++ks)
#pragma unroll
            for (int nj = 0; nj < 2; ++nj) {
                size_t word = ((size_t)((st * 4 + ks) * 16 + wn * 2 + nj)) * 64 + lane;
                br[ks * 2 + nj] = *(const uint4*)&bp[word * 8];
            }
    };

    f32x4 acc[4][2];
#pragma unroll
    for (int mi = 0; mi < 4; ++mi)
#pragma unroll
        for (int nj = 0; nj < 2; ++nj) { f32x4 z = {0.f,0.f,0.f,0.f}; acc[mi][nj] = z; }

    auto MFMA32 = [&](int buf, uint4* br) {
        __builtin_amdgcn_s_setprio(1);
#pragma unroll
        for (int ks = 0; ks < 4; ++ks) {
            const int cg = ks * 4 + kg;
            union { uint4 q; h8 h; } b0, b1;
            b0.q = br[ks * 2]; b1.q = br[ks * 2 + 1];
#pragma unroll
            for (int mi = 0; mi < 4; ++mi) {
                int w = cg * 64 + ((mi * 16 + colg) ^ (cg & 7));
                h8 a = *(const h8*)&Asl[buf][w * 8];
                acc[mi][0] = __builtin_amdgcn_mfma_f32_16x16x32_f16(a, b0.h, acc[mi][0], 0, 0, 0);
                acc[mi][1] = __builtin_amdgcn_mfma_f32_16x16x32_f16(a, b1.h, acc[mi][1], 0, 0, 0);
            }
        }
        __builtin_amdgcn_s_setprio(0);
    };

    h8 C[8];
    uint4 breg[8], bnext[8];

    AGLOAD(0, C);
    BLOAD(0, breg);
    GCONSUME(0, 0, C);
    __syncthreads();

    for (int s = 0; s < 18; ++s) {
        const int cur = s & 1;
        if (s + 1 < 18) {
            AGLOAD(s + 1, C);             // corner prefetch in flight over MFMAs
            BLOAD(s + 1, bnext);          // B prefetch in flight
        }
        MFMA32(cur, breg);
        if (s + 1 < 18) GCONSUME(s + 1, cur ^ 1, C);
        __syncthreads();
#pragma unroll
        for (int i = 0; i < 8; ++i) breg[i] = bnext[i];
    }

    // ---- epilogue: col=lane&15 -> co, row=(lane>>4)*4+reg -> px ----
#pragma unroll
    for (int nj = 0; nj < 2; ++nj) {
        const int co = wn * 32 + nj * 16 + colg;
        const float bv = db[co];
        float* op = out + ((size_t)(b * COUT + co) << 12) + rowbase + kg * 4;
#pragma unroll
        for (int mi = 0; mi < 4; ++mi) {
            float4 o;
            o.x = acc[mi][nj][0] + bv;
            o.y = acc[mi][nj][1] + bv;
            o.z = acc[mi][nj][2] + bv;
            o.w = acc[mi][nj][3] + bv;
            *(float4*)&op[mi * 16] = o;
        }
    }
}

// ---------------------------------------------------------------------------
extern "C" void kernel_launch(void* const* d_in, const int* in_sizes, int n_in,
                              void* d_out, int out_size, void* d_ws, size_t ws_size,
                              hipStream_t stream)
{
    const float* x  = (const float*)d_in[0];
    const float* ow = (const float*)d_in[1];
    const float* ob = (const float*)d_in[2];
    const float* dw = (const float*)d_in[3];
    const float* db = (const float*)d_in[4];
    float* out = (float*)d_out;

    // ws layout (bytes):
    // opart f32 [2][4][18][4096] = 2359296 | bp f16 1179648 | bow f16 147456 | xT f16 8388608
    char* wsp = (char*)d_ws;
    float*     opart = (float*)wsp;
    _Float16*  bp    = (_Float16*)(wsp + 2359296);
    _Float16*  bow   = (_Float16*)(wsp + 3538944);
    _Float16*  xT    = (_Float16*)(wsp + 3686400);

    hipLaunchKernelGGL(prework_kernel,     dim3(1348), dim3(256), 0, stream, x, ow, dw, xT, bp, bow);
    hipLaunchKernelGGL(offset_mfma_kernel, dim3(256),  dim3(512), 0, stream, xT, bow, opart);
    hipLaunchKernelGGL(dcn_mfma_kernel,    dim3(256),  dim3(512), 0, stream, xT, opart, ob, bp, db, out);
}

// Round 12
// 70.663 us; speedup vs baseline: 1.8845x; 1.0082x over previous
//
#include <hip/hip_runtime.h>

#define BB 4
#define CIN 256
#define COUT 256
#define HH 64
#define WW 64
#define KK 9
#define OC2 18
#define KTOT (CIN * KK)        // 2304 = 72 x 32-k steps = 18 x 128-k stages

typedef __attribute__((ext_vector_type(8))) _Float16 h8;
typedef __attribute__((ext_vector_type(4))) float f32x4;

static __device__ __forceinline__ h8 splat_pk(unsigned pk) {
    union { unsigned u[4]; h8 h; } s;
    s.u[0] = pk; s.u[1] = pk; s.u[2] = pk; s.u[3] = pk;
    return s.h;
}

// ---------------------------------------------------------------------------
// Kernel 1 (fused prework):
//   blocks 0..1023    : transpose x [B][C][H][W] f32 -> xT [B][px][256c] f16
//   blocks 1024..1311 : pack dcn_w -> bp fragments
//   blocks 1312..1347 : pack offset_w -> bow fragments (oc padded 18->32)
// ---------------------------------------------------------------------------
__global__ __launch_bounds__(256) void prework_kernel(
    const float* __restrict__ x, const float* __restrict__ ow,
    const float* __restrict__ dw,
    _Float16* __restrict__ xT, _Float16* __restrict__ bp,
    _Float16* __restrict__ bow)
{
    const int bid = blockIdx.x;
    const int t = threadIdx.x;
    if (bid < 1024) {
        const int b = bid >> 8, y = (bid >> 2) & 63, c0 = (bid & 3) * 64;
        __shared__ float tile[64][65];
#pragma unroll
        for (int r = 0; r < 16; ++r) {
            int idx = r * 256 + t;
            int c = idx >> 6, w = idx & 63;
            tile[c][w] = x[(((size_t)(b * CIN + c0 + c)) << 12) + (y << 6) + w];
        }
        __syncthreads();
        const int px = t >> 2;
#pragma unroll
        for (int half = 0; half < 2; ++half) {
            int cc = (t & 3) + half * 4;
            union { _Float16 h[8]; uint4 q; } u;
#pragma unroll
            for (int j = 0; j < 8; ++j) u.h[j] = (_Float16)tile[cc * 8 + j][px];
            size_t el = (((size_t)(b << 12)) + (y << 6) + px) * 256 + c0 + cc * 8;
            *(uint4*)&xT[el] = u.q;
        }
    } else if (bid < 1312) {
        // pack dcn_w: word wid = (T*16 + cotile)*64 + lane (T = 32-k step)
        int wid = (bid - 1024) * 256 + t;
        int T = wid >> 10;
        int r = wid & 1023;
        int cotile = r >> 6, lane = r & 63;
        int co = cotile * 16 + (lane & 15);
        int kbase = T * 32 + ((lane >> 4) & 3) * 8;
        union { _Float16 h[8]; uint4 q; } u;
#pragma unroll
        for (int j = 0; j < 8; ++j) {
            int k = kbase + j;
            int c = k & 255, kk = k >> 8;
            u.h[j] = (_Float16)dw[co * KTOT + c * KK + kk];
        }
        *(uint4*)&bp[(size_t)wid * 8] = u.q;
    } else {
        // pack offset_w (oc padded 18->32): wid = (T*2+nj)*64+lane
        int wid = (bid - 1312) * 256 + t;
        int T = wid >> 7;
        int r = wid & 127;
        int lane = r & 63;
        int oc = ((r >> 6) << 4) + (lane & 15);
        int kbase = T * 32 + ((lane >> 4) & 3) * 8;
        union { _Float16 h[8]; uint4 q; } u;
#pragma unroll
        for (int j = 0; j < 8; ++j) {
            int k = kbase + j;
            int c = k & 255, kk = k >> 8;
            u.h[j] = (oc < OC2) ? (_Float16)ow[oc * KTOT + c * KK + kk] : (_Float16)0.f;
        }
        *(uint4*)&bow[(size_t)wid * 8] = u.q;
    }
}

// ---------------------------------------------------------------------------
// Kernel 2: offset conv, ZERO-LDS barrier-free streaming MFMA. 256 blocks =
// 128 m-tiles(128px) x 2 K-halves; 512 thr = 8 waves, wave = 16px x 32co.
// ---------------------------------------------------------------------------
__global__ __launch_bounds__(512) void offset_mfma_kernel(
    const _Float16* __restrict__ xT, const _Float16* __restrict__ bow,
    float* __restrict__ opart)
{
    const int bid = blockIdx.x;
    const int m_blk = bid >> 1, kh = bid & 1;
    const int b = m_blk >> 5;
    const int pxbase = (m_blk & 31) * 128;
    const int tid = threadIdx.x;
    const int lane = tid & 63, wv = tid >> 6;
    const int colg = lane & 15, kg = lane >> 4;

    const int pxl = pxbase + (wv << 4) + colg;
    const int py = pxl >> 6, pxx = pxl & 63;

    const _Float16* xb = xT + ((size_t)b << 20);

    auto GLOAD = [&](int T, h8& R) {
        int kk = T >> 3;
        int ky = kk / 3, kx = kk - 3 * (kk / 3);
        int yy = py + ky - 1, xx = pxx + kx - 1;
        h8 v = {0, 0, 0, 0, 0, 0, 0, 0};
        if ((unsigned)yy < HH && (unsigned)xx < WW)
            v = *(const h8*)(xb + ((((yy << 6) + xx) << 8) + ((T & 7) << 5) + (kg << 3)));
        R = v;
    };
    auto BLOAD = [&](int T, uint4* br) {
#pragma unroll
        for (int nj = 0; nj < 2; ++nj)
            br[nj] = *(const uint4*)&bow[(size_t)(((T << 1) + nj) * 64 + lane) * 8];
    };

    f32x4 acc[2];
    { f32x4 z = {0.f, 0.f, 0.f, 0.f}; acc[0] = z; acc[1] = z; }

    const int Tb = kh * 36;
    h8 E, F;
    uint4 bA[2], bB[2];

    GLOAD(Tb, E);
    BLOAD(Tb, bA);
    for (int r = 0; r < 36; r += 2) {
        GLOAD(Tb + r + 1, F);
        BLOAD(Tb + r + 1, bB);
        {
            union { uint4 q; h8 h; } u0, u1;
            u0.q = bA[0]; u1.q = bA[1];
            acc[0] = __builtin_amdgcn_mfma_f32_16x16x32_f16(E, u0.h, acc[0], 0, 0, 0);
            acc[1] = __builtin_amdgcn_mfma_f32_16x16x32_f16(E, u1.h, acc[1], 0, 0, 0);
        }
        if (r + 2 < 36) { GLOAD(Tb + r + 2, E); BLOAD(Tb + r + 2, bA); }
        {
            union { uint4 q; h8 h; } u0, u1;
            u0.q = bB[0]; u1.q = bB[1];
            acc[0] = __builtin_amdgcn_mfma_f32_16x16x32_f16(F, u0.h, acc[0], 0, 0, 0);
            acc[1] = __builtin_amdgcn_mfma_f32_16x16x32_f16(F, u1.h, acc[1], 0, 0, 0);
        }
    }

    const int pxb = pxbase + (wv << 4) + kg * 4;
#pragma unroll
    for (int nj = 0; nj < 2; ++nj) {
        int oc = nj * 16 + colg;
        if (oc < OC2) {
            float4 o;
            o.x = acc[nj][0]; o.y = acc[nj][1];
            o.z = acc[nj][2]; o.w = acc[nj][3];
            *(float4*)&opart[(((size_t)((kh * BB + b) * OC2 + oc)) << 12) + pxb] = o;
        }
    }
}

// ---------------------------------------------------------------------------
// Kernel 3: fused bilinear-gather + MFMA implicit GEMM (fp16), v12.
// 512 blocks (32px x 256co) = 2 blocks/CU (the R11 fix: barrier drains of one
// block overlap with the other block's work). 512 thr = 8 waves = 8 N-SLICES
// (wave = 32px x 32co: 2 m-frags x 2 n-frags, 8 A-reads -> 16 MFMA / stage).
// A in LDS once per block (XOR layout word = cg*32 + (px ^ (cg&7)) --
// write & read both 2-way max); B global -> regs (per-wave co slice; B
// L2-resident). 1-word/thread gather, 1-stage prefetch on A and B.
// ---------------------------------------------------------------------------
__global__ __launch_bounds__(512, 4) void dcn_mfma_kernel(
    const _Float16* __restrict__ xT, const float* __restrict__ opart,
    const float* __restrict__ ob, const _Float16* __restrict__ bp,
    const float* __restrict__ db, float* __restrict__ out)
{
    __shared__ __align__(16) _Float16 Asl[2][512 * 8];   // 8 KB per buf
    __shared__ __align__(8) uint2 twp[288];              // packed bilinear wgts
    __shared__ __align__(8) uint2 tih[288];              // packed corner px idx

    int P = blockIdx.x;
    int L = (P & 7) * 64 + (P >> 3);      // XCD swizzle (512 % 8 == 0)
    const int b = L >> 7;
    const int rowbase = (L & 127) * 32;   // 32-px m-tile

    const int tid = threadIdx.x;
    const int lane = tid & 63;
    const int wn = tid >> 6;              // 0..7 = co slice (32 co)
    const int colg = lane & 15, kg = lane >> 4;

    // gather role: one A word per thread per stage
    const int g_px = tid >> 4;            // 0..31 px within tile
    const int g_cg = tid & 15;            // 8-ch chunk within 128-k stage
    const int g_ebase = g_px * 9;
    // XOR layout: word(cg, px) = cg*32 + (px ^ (cg&7))
    const int g_w0 = g_cg * 32 + (g_px ^ (g_cg & 7));

    // ---- bilinear table: 32 px x 9 taps (merge split-K partials + bias) ----
    const float* op0 = opart + (((size_t)(b * OC2)) << 12);
    const float* op1 = opart + (((size_t)((BB + b) * OC2)) << 12);
    if (tid < 288) {
        int e = tid;
        int p = e / 9, kk = e - (e / 9) * 9;
        int pxl = rowbase + p;
        int y = pxl >> 6, xx = pxl & 63;
        float dy = op0[((size_t)(2 * kk) << 12) + pxl]
                 + op1[((size_t)(2 * kk) << 12) + pxl] + ob[2 * kk];
        float dx = op0[((size_t)(2 * kk + 1) << 12) + pxl]
                 + op1[((size_t)(2 * kk + 1) << 12) + pxl] + ob[2 * kk + 1];
        int ky = kk / 3, kx = kk - 3 * (kk / 3);
        float sy = (float)(y - 1 + ky) + dy;
        float sx = (float)(xx - 1 + kx) + dx;
        float fy = floorf(sy), fx = floorf(sx);
        int y0 = (int)fy, x0 = (int)fx;
        float wy1 = sy - fy, wx1 = sx - fx;
        float wy0 = 1.f - wy1, wx0 = 1.f - wx1;
        bool vy0 = (unsigned)y0 < HH, vy1 = (unsigned)(y0 + 1) < HH;
        bool vx0 = (unsigned)x0 < WW, vx1 = (unsigned)(x0 + 1) < WW;
        _Float16 w00 = (_Float16)((vy0 && vx0) ? wy0 * wx0 : 0.f);
        _Float16 w01 = (_Float16)((vy0 && vx1) ? wy0 * wx1 : 0.f);
        _Float16 w10 = (_Float16)((vy1 && vx0) ? wy1 * wx0 : 0.f);
        _Float16 w11 = (_Float16)((vy1 && vx1) ? wy1 * wx1 : 0.f);
        union { _Float16 h[2]; unsigned u; } pk2;
        uint2 W;
        pk2.h[0] = w00; pk2.h[1] = w01; W.x = pk2.u;
        pk2.h[0] = w10; pk2.h[1] = w11; W.y = pk2.u;
        twp[e] = W;
        int y0c = min(max(y0, 0), HH - 1), y1c = min(max(y0 + 1, 0), HH - 1);
        int x0c = min(max(x0, 0), WW - 1), x1c = min(max(x0 + 1, 0), WW - 1);
        unsigned i00 = (unsigned)((y0c << 6) + x0c);
        unsigned i01 = (unsigned)((y0c << 6) + x1c);
        unsigned i10 = (unsigned)((y1c << 6) + x0c);
        unsigned i11 = (unsigned)((y1c << 6) + x1c);
        tih[e] = make_uint2(i00 | (i01 << 16), i10 | (i11 << 16));
    }
    __syncthreads();

    const char* xbyte = (const char*)(xT + ((size_t)b << 20));  // uniform

    // 4 coalesced corner loads for stage st (16 lanes share px -> 256B/line grp)
    auto AGLOAD = [&](int st, h8* C) {
        uint2 ij = tih[g_ebase + (st >> 1)];
        unsigned chb = (unsigned)((st & 1) * 256 + g_cg * 16);
        C[0] = *(const h8*)(xbyte + (((ij.x & 0xFFFFu) << 9) + chb));
        C[1] = *(const h8*)(xbyte + (((ij.x >> 16)     << 9) + chb));
        C[2] = *(const h8*)(xbyte + (((ij.y & 0xFFFFu) << 9) + chb));
        C[3] = *(const h8*)(xbyte + (((ij.y >> 16)     << 9) + chb));
    };
    // combine + 1 ds_write (vm-wait for C lands here, after the MFMAs)
    auto GCONSUME = [&](int st, int buf, const h8* C) {
        uint2 w = twp[g_ebase + (st >> 1)];
        unsigned w00 = (w.x & 0xFFFFu) * 0x10001u;
        unsigned w01 = (w.x >> 16)     * 0x10001u;
        unsigned w10 = (w.y & 0xFFFFu) * 0x10001u;
        unsigned w11 = (w.y >> 16)     * 0x10001u;
        h8 v = C[0] * splat_pk(w00);
        v += C[1] * splat_pk(w01);
        v += C[2] * splat_pk(w10);
        v += C[3] * splat_pk(w11);
        *(h8*)&Asl[buf][g_w0 * 8] = v;
    };
    // B: 8 words per wave per stage (4 ks x 2 nj), own 32-co slice only
    auto BLOAD = [&](int st, uint4* br) {
#pragma unroll
        for (int ks = 0; ks < 4; ++ks)
#pragma unroll
            for (int nj = 0; nj < 2; ++nj) {
                size_t word = ((size_t)((st * 4 + ks) * 16 + wn * 2 + nj)) * 64 + lane;
                br[ks * 2 + nj] = *(const uint4*)&bp[word * 8];
            }
    };

    f32x4 acc[2][2];
#pragma unroll
    for (int mi = 0; mi < 2; ++mi)
#pragma unroll
        for (int nj = 0; nj < 2; ++nj) { f32x4 z = {0.f,0.f,0.f,0.f}; acc[mi][nj] = z; }

    auto MFMA16 = [&](int buf, uint4* br) {
        __builtin_amdgcn_s_setprio(1);
#pragma unroll
        for (int ks = 0; ks < 4; ++ks) {
            const int cg = ks * 4 + kg;
            union { uint4 q; h8 h; } b0, b1;
            b0.q = br[ks * 2]; b1.q = br[ks * 2 + 1];
#pragma unroll
            for (int mi = 0; mi < 2; ++mi) {
                int w = cg * 32 + ((mi * 16 + colg) ^ (cg & 7));
                h8 a = *(const h8*)&Asl[buf][w * 8];
                acc[mi][0] = __builtin_amdgcn_mfma_f32_16x16x32_f16(a, b0.h, acc[mi][0], 0, 0, 0);
                acc[mi][1] = __builtin_amdgcn_mfma_f32_16x16x32_f16(a, b1.h, acc[mi][1], 0, 0, 0);
            }
        }
        __builtin_amdgcn_s_setprio(0);
    };

    h8 C[4];
    uint4 breg[8], bnext[8];

    AGLOAD(0, C);
    BLOAD(0, breg);
    GCONSUME(0, 0, C);
    __syncthreads();

    for (int s = 0; s < 18; ++s) {
        const int cur = s & 1;
        if (s + 1 < 18) {
            AGLOAD(s + 1, C);             // corner prefetch in flight over MFMAs
            BLOAD(s + 1, bnext);          // B prefetch in flight
        }
        MFMA16(cur, breg);
        if (s + 1 < 18) GCONSUME(s + 1, cur ^ 1, C);
        __syncthreads();
#pragma unroll
        for (int i = 0; i < 8; ++i) breg[i] = bnext[i];
    }

    // ---- epilogue: col=lane&15 -> co, row=(lane>>4)*4+reg -> px ----
#pragma unroll
    for (int nj = 0; nj < 2; ++nj) {
        const int co = wn * 32 + nj * 16 + colg;
        const float bv = db[co];
        float* op = out + ((size_t)(b * COUT + co) << 12) + rowbase + kg * 4;
#pragma unroll
        for (int mi = 0; mi < 2; ++mi) {
            float4 o;
            o.x = acc[mi][nj][0] + bv;
            o.y = acc[mi][nj][1] + bv;
            o.z = acc[mi][nj][2] + bv;
            o.w = acc[mi][nj][3] + bv;
            *(float4*)&op[mi * 16] = o;
        }
    }
}

// ---------------------------------------------------------------------------
extern "C" void kernel_launch(void* const* d_in, const int* in_sizes, int n_in,
                              void* d_out, int out_size, void* d_ws, size_t ws_size,
                              hipStream_t stream)
{
    const float* x  = (const float*)d_in[0];
    const float* ow = (const float*)d_in[1];
    const float* ob = (const float*)d_in[2];
    const float* dw = (const float*)d_in[3];
    const float* db = (const float*)d_in[4];
    float* out = (float*)d_out;

    // ws layout (bytes):
    // opart f32 [2][4][18][4096] = 2359296 | bp f16 1179648 | bow f16 147456 | xT f16 8388608
    char* wsp = (char*)d_ws;
    float*     opart = (float*)wsp;
    _Float16*  bp    = (_Float16*)(wsp + 2359296);
    _Float16*  bow   = (_Float16*)(wsp + 3538944);
    _Float16*  xT    = (_Float16*)(wsp + 3686400);

    hipLaunchKernelGGL(prework_kernel,     dim3(1348), dim3(256), 0, stream, x, ow, dw, xT, bp, bow);
    hipLaunchKernelGGL(offset_mfma_kernel, dim3(256),  dim3(512), 0, stream, xT, bow, opart);
    hipLaunchKernelGGL(dcn_mfma_kernel,    dim3(512),  dim3(512), 0, stream, xT, opart, ob, bp, db, out);
}

// Round 13
// 63.435 us; speedup vs baseline: 2.0992x; 1.1139x over previous
//
#include <hip/hip_runtime.h>

#define BB 4
#define CIN 256
#define COUT 256
#define HH 64
#define WW 64
#define KK 9
#define OC2 18
#define KTOT (CIN * KK)        // 2304 = 72 x 32-k steps = 18 x 128-k stages

typedef __attribute__((ext_vector_type(8))) _Float16 h8;
typedef __attribute__((ext_vector_type(4))) float f32x4;

static __device__ __forceinline__ h8 splat_pk(unsigned pk) {
    union { unsigned u[4]; h8 h; } s;
    s.u[0] = pk; s.u[1] = pk; s.u[2] = pk; s.u[3] = pk;
    return s.h;
}

// ---------------------------------------------------------------------------
// Kernel 1 (fused prework):
//   blocks 0..1023    : transpose x [B][C][H][W] f32 -> xT [B][px][256c] f16
//   blocks 1024..1311 : pack dcn_w -> bp fragments
//   blocks 1312..1347 : pack offset_w -> bow fragments (oc padded 18->32)
// ---------------------------------------------------------------------------
__global__ __launch_bounds__(256) void prework_kernel(
    const float* __restrict__ x, const float* __restrict__ ow,
    const float* __restrict__ dw,
    _Float16* __restrict__ xT, _Float16* __restrict__ bp,
    _Float16* __restrict__ bow)
{
    const int bid = blockIdx.x;
    const int t = threadIdx.x;
    if (bid < 1024) {
        const int b = bid >> 8, y = (bid >> 2) & 63, c0 = (bid & 3) * 64;
        __shared__ float tile[64][65];
#pragma unroll
        for (int r = 0; r < 16; ++r) {
            int idx = r * 256 + t;
            int c = idx >> 6, w = idx & 63;
            tile[c][w] = x[(((size_t)(b * CIN + c0 + c)) << 12) + (y << 6) + w];
        }
        __syncthreads();
        const int px = t >> 2;
#pragma unroll
        for (int half = 0; half < 2; ++half) {
            int cc = (t & 3) + half * 4;
            union { _Float16 h[8]; uint4 q; } u;
#pragma unroll
            for (int j = 0; j < 8; ++j) u.h[j] = (_Float16)tile[cc * 8 + j][px];
            size_t el = (((size_t)(b << 12)) + (y << 6) + px) * 256 + c0 + cc * 8;
            *(uint4*)&xT[el] = u.q;
        }
    } else if (bid < 1312) {
        // pack dcn_w: word wid = (T*16 + cotile)*64 + lane (T = 32-k step)
        int wid = (bid - 1024) * 256 + t;
        int T = wid >> 10;
        int r = wid & 1023;
        int cotile = r >> 6, lane = r & 63;
        int co = cotile * 16 + (lane & 15);
        int kbase = T * 32 + ((lane >> 4) & 3) * 8;
        union { _Float16 h[8]; uint4 q; } u;
#pragma unroll
        for (int j = 0; j < 8; ++j) {
            int k = kbase + j;
            int c = k & 255, kk = k >> 8;
            u.h[j] = (_Float16)dw[co * KTOT + c * KK + kk];
        }
        *(uint4*)&bp[(size_t)wid * 8] = u.q;
    } else {
        // pack offset_w (oc padded 18->32): wid = (T*2+nj)*64+lane
        int wid = (bid - 1312) * 256 + t;
        int T = wid >> 7;
        int r = wid & 127;
        int lane = r & 63;
        int oc = ((r >> 6) << 4) + (lane & 15);
        int kbase = T * 32 + ((lane >> 4) & 3) * 8;
        union { _Float16 h[8]; uint4 q; } u;
#pragma unroll
        for (int j = 0; j < 8; ++j) {
            int k = kbase + j;
            int c = k & 255, kk = k >> 8;
            u.h[j] = (oc < OC2) ? (_Float16)ow[oc * KTOT + c * KK + kk] : (_Float16)0.f;
        }
        *(uint4*)&bow[(size_t)wid * 8] = u.q;
    }
}

// ---------------------------------------------------------------------------
// Kernel 2: fused {offset-conv + bilinear-gather + MFMA implicit GEMM}, v13.
// 512 blocks (32px x 256co) = 2/CU, 512 thr = 8 waves.
//
// Phase 0 (new): in-block offset conv. M=32px x N=32(18 oc) x K=2304, K
//   split across the 8 waves (9 of the 72 32-k steps each, aligned taps from
//   xT, bow as B). Partials to 32 KB LDS scratch (aliases the A-buffers);
//   summed in FIXED wave order by the table-build threads (deterministic).
// Phase 1: bilinear table from in-LDS offsets (no opart global round-trip).
// Phase 2: 18-stage main loop — identical to R12 (stable at ~45 us):
//   A gathered once per block to XOR-layout LDS (conflict-free), B direct
//   global->regs per 32-co wave slice, 1-stage prefetch on A and B.
// ---------------------------------------------------------------------------
__global__ __launch_bounds__(512, 4) void dcn_mfma_kernel(
    const _Float16* __restrict__ xT, const _Float16* __restrict__ bow,
    const float* __restrict__ ob, const _Float16* __restrict__ bp,
    const float* __restrict__ db, float* __restrict__ out)
{
    // smem: [0,32768) = offset scratch f32[8][32][32]  (later aliased by
    //       Asl[2][4096] halves = 16 KB);  [32768,37376) twp; [37376,41984) tih
    __shared__ __align__(16) char smem[32768 + 4608 + 4608];
    _Float16 (*Asl)[4096] = (_Float16(*)[4096])smem;
    float* oscr = (float*)smem;
    uint2* twp = (uint2*)(smem + 32768);
    uint2* tih = (uint2*)(smem + 32768 + 4608);

    int P = blockIdx.x;
    int L = (P & 7) * 64 + (P >> 3);      // XCD swizzle (512 % 8 == 0)
    const int b = L >> 7;
    const int rowbase = (L & 127) * 32;   // 32-px m-tile

    const int tid = threadIdx.x;
    const int lane = tid & 63;
    const int wn = tid >> 6;              // 0..7 = co slice (32 co) / K-slice
    const int colg = lane & 15, kg = lane >> 4;

    const char* xbyte = (const char*)(xT + ((size_t)b << 20));  // uniform

    // ================= Phase 0: in-block offset conv =================
    {
        f32x4 oacc[2][2];
#pragma unroll
        for (int mi = 0; mi < 2; ++mi)
#pragma unroll
            for (int nj = 0; nj < 2; ++nj) { f32x4 z = {0.f,0.f,0.f,0.f}; oacc[mi][nj] = z; }

        const int T0 = wn * 9;            // this wave's K-slice
#pragma unroll
        for (int i = 0; i < 9; ++i) {
            int T = T0 + i;
            int kk = T >> 3;
            int ky = kk / 3, kx = kk - 3 * (kk / 3);
            int cgo = ((T & 7) << 2) + kg;       // channel grp 0..31
            h8 a[2];
#pragma unroll
            for (int mi = 0; mi < 2; ++mi) {
                int pxl = rowbase + mi * 16 + colg;
                int yy = (pxl >> 6) + ky - 1, xx = (pxl & 63) + kx - 1;
                h8 v = {0,0,0,0,0,0,0,0};
                if ((unsigned)yy < HH && (unsigned)xx < WW)
                    v = *(const h8*)(xbyte + ((((yy << 6) + xx) << 9) + (cgo << 4)));
                a[mi] = v;
            }
            union { uint4 q; h8 h; } bw[2];
#pragma unroll
            for (int nj = 0; nj < 2; ++nj)
                bw[nj].q = *(const uint4*)&bow[(size_t)(((T << 1) + nj) * 64 + lane) * 8];
#pragma unroll
            for (int mi = 0; mi < 2; ++mi)
#pragma unroll
                for (int nj = 0; nj < 2; ++nj)
                    oacc[mi][nj] = __builtin_amdgcn_mfma_f32_16x16x32_f16(
                        a[mi], bw[nj].h, oacc[mi][nj], 0, 0, 0);
        }
        // partials -> scratch [w][px(32)][oc(32)]
#pragma unroll
        for (int mi = 0; mi < 2; ++mi)
#pragma unroll
            for (int nj = 0; nj < 2; ++nj) {
                int px0 = mi * 16 + kg * 4;
                int oc = nj * 16 + colg;
#pragma unroll
                for (int r = 0; r < 4; ++r)
                    oscr[(wn * 32 + px0 + r) * 32 + oc] = oacc[mi][nj][r];
            }
    }
    __syncthreads();

    // ================= Phase 1: bilinear table (32 px x 9 taps) ==========
    if (tid < 288) {
        int e = tid;
        int p = e / 9, kk = e - (e / 9) * 9;
        float dy = ob[2 * kk], dx = ob[2 * kk + 1];
#pragma unroll
        for (int w2 = 0; w2 < 8; ++w2) {          // fixed order: deterministic
            dy += oscr[(w2 * 32 + p) * 32 + 2 * kk];
            dx += oscr[(w2 * 32 + p) * 32 + 2 * kk + 1];
        }
        int pxl = rowbase + p;
        int y = pxl >> 6, xx = pxl & 63;
        int ky = kk / 3, kx = kk - 3 * (kk / 3);
        float sy = (float)(y - 1 + ky) + dy;
        float sx = (float)(xx - 1 + kx) + dx;
        float fy = floorf(sy), fx = floorf(sx);
        int y0 = (int)fy, x0 = (int)fx;
        float wy1 = sy - fy, wx1 = sx - fx;
        float wy0 = 1.f - wy1, wx0 = 1.f - wx1;
        bool vy0 = (unsigned)y0 < HH, vy1 = (unsigned)(y0 + 1) < HH;
        bool vx0 = (unsigned)x0 < WW, vx1 = (unsigned)(x0 + 1) < WW;
        _Float16 w00 = (_Float16)((vy0 && vx0) ? wy0 * wx0 : 0.f);
        _Float16 w01 = (_Float16)((vy0 && vx1) ? wy0 * wx1 : 0.f);
        _Float16 w10 = (_Float16)((vy1 && vx0) ? wy1 * wx0 : 0.f);
        _Float16 w11 = (_Float16)((vy1 && vx1) ? wy1 * wx1 : 0.f);
        union { _Float16 h[2]; unsigned u; } pk2;
        uint2 W;
        pk2.h[0] = w00; pk2.h[1] = w01; W.x = pk2.u;
        pk2.h[0] = w10; pk2.h[1] = w11; W.y = pk2.u;
        twp[e] = W;
        int y0c = min(max(y0, 0), HH - 1), y1c = min(max(y0 + 1, 0), HH - 1);
        int x0c = min(max(x0, 0), WW - 1), x1c = min(max(x0 + 1, 0), WW - 1);
        unsigned i00 = (unsigned)((y0c << 6) + x0c);
        unsigned i01 = (unsigned)((y0c << 6) + x1c);
        unsigned i10 = (unsigned)((y1c << 6) + x0c);
        unsigned i11 = (unsigned)((y1c << 6) + x1c);
        tih[e] = make_uint2(i00 | (i01 << 16), i10 | (i11 << 16));
    }
    __syncthreads();   // tables visible; scratch reads done (Asl may now alias)

    // ================= Phase 2: main implicit GEMM (identical to R12) ====
    // gather role: one A word per thread per stage
    const int g_px = tid >> 4;            // 0..31 px within tile
    const int g_cg = tid & 15;            // 8-ch chunk within 128-k stage
    const int g_ebase = g_px * 9;
    const int g_w0 = g_cg * 32 + (g_px ^ (g_cg & 7));   // XOR layout

    auto AGLOAD = [&](int st, h8* C) {
        uint2 ij = tih[g_ebase + (st >> 1)];
        unsigned chb = (unsigned)((st & 1) * 256 + g_cg * 16);
        C[0] = *(const h8*)(xbyte + (((ij.x & 0xFFFFu) << 9) + chb));
        C[1] = *(const h8*)(xbyte + (((ij.x >> 16)     << 9) + chb));
        C[2] = *(const h8*)(xbyte + (((ij.y & 0xFFFFu) << 9) + chb));
        C[3] = *(const h8*)(xbyte + (((ij.y >> 16)     << 9) + chb));
    };
    auto GCONSUME = [&](int st, int buf, const h8* C) {
        uint2 w = twp[g_ebase + (st >> 1)];
        unsigned w00 = (w.x & 0xFFFFu) * 0x10001u;
        unsigned w01 = (w.x >> 16)     * 0x10001u;
        unsigned w10 = (w.y & 0xFFFFu) * 0x10001u;
        unsigned w11 = (w.y >> 16)     * 0x10001u;
        h8 v = C[0] * splat_pk(w00);
        v += C[1] * splat_pk(w01);
        v += C[2] * splat_pk(w10);
        v += C[3] * splat_pk(w11);
        *(h8*)&Asl[buf][g_w0 * 8] = v;
    };
    auto BLOAD = [&](int st, uint4* br) {
#pragma unroll
        for (int ks = 0; ks < 4; ++ks)
#pragma unroll
            for (int nj = 0; nj < 2; ++nj) {
                size_t word = ((size_t)((st * 4 + ks) * 16 + wn * 2 + nj)) * 64 + lane;
                br[ks * 2 + nj] = *(const uint4*)&bp[word * 8];
            }
    };

    f32x4 acc[2][2];
#pragma unroll
    for (int mi = 0; mi < 2; ++mi)
#pragma unroll
        for (int nj = 0; nj < 2; ++nj) { f32x4 z = {0.f,0.f,0.f,0.f}; acc[mi][nj] = z; }

    auto MFMA16 = [&](int buf, uint4* br) {
        __builtin_amdgcn_s_setprio(1);
#pragma unroll
        for (int ks = 0; ks < 4; ++ks) {
            const int cg = ks * 4 + kg;
            union { uint4 q; h8 h; } b0, b1;
            b0.q = br[ks * 2]; b1.q = br[ks * 2 + 1];
#pragma unroll
            for (int mi = 0; mi < 2; ++mi) {
                int w = cg * 32 + ((mi * 16 + colg) ^ (cg & 7));
                h8 a = *(const h8*)&Asl[buf][w * 8];
                acc[mi][0] = __builtin_amdgcn_mfma_f32_16x16x32_f16(a, b0.h, acc[mi][0], 0, 0, 0);
                acc[mi][1] = __builtin_amdgcn_mfma_f32_16x16x32_f16(a, b1.h, acc[mi][1], 0, 0, 0);
            }
        }
        __builtin_amdgcn_s_setprio(0);
    };

    h8 C[4];
    uint4 breg[8], bnext[8];

    AGLOAD(0, C);
    BLOAD(0, breg);
    GCONSUME(0, 0, C);
    __syncthreads();

    for (int s = 0; s < 18; ++s) {
        const int cur = s & 1;
        if (s + 1 < 18) {
            AGLOAD(s + 1, C);             // corner prefetch in flight over MFMAs
            BLOAD(s + 1, bnext);          // B prefetch in flight
        }
        MFMA16(cur, breg);
        if (s + 1 < 18) GCONSUME(s + 1, cur ^ 1, C);
        __syncthreads();
#pragma unroll
        for (int i = 0; i < 8; ++i) breg[i] = bnext[i];
    }

    // ---- epilogue: col=lane&15 -> co, row=(lane>>4)*4+reg -> px ----
#pragma unroll
    for (int nj = 0; nj < 2; ++nj) {
        const int co = wn * 32 + nj * 16 + colg;
        const float bv = db[co];
        float* op = out + ((size_t)(b * COUT + co) << 12) + rowbase + kg * 4;
#pragma unroll
        for (int mi = 0; mi < 2; ++mi) {
            float4 o;
            o.x = acc[mi][nj][0] + bv;
            o.y = acc[mi][nj][1] + bv;
            o.z = acc[mi][nj][2] + bv;
            o.w = acc[mi][nj][3] + bv;
            *(float4*)&op[mi * 16] = o;
        }
    }
}

// ---------------------------------------------------------------------------
extern "C" void kernel_launch(void* const* d_in, const int* in_sizes, int n_in,
                              void* d_out, int out_size, void* d_ws, size_t ws_size,
                              hipStream_t stream)
{
    const float* x  = (const float*)d_in[0];
    const float* ow = (const float*)d_in[1];
    const float* ob = (const float*)d_in[2];
    const float* dw = (const float*)d_in[3];
    const float* db = (const float*)d_in[4];
    float* out = (float*)d_out;

    // ws layout (bytes): bp f16 1179648 | bow f16 147456 | xT f16 8388608
    char* wsp = (char*)d_ws;
    _Float16*  bp  = (_Float16*)wsp;
    _Float16*  bow = (_Float16*)(wsp + 1179648);
    _Float16*  xT  = (_Float16*)(wsp + 1327104);

    hipLaunchKernelGGL(prework_kernel,  dim3(1348), dim3(256), 0, stream, x, ow, dw, xT, bp, bow);
    hipLaunchKernelGGL(dcn_mfma_kernel, dim3(512),  dim3(512), 0, stream, xT, bow, ob, bp, db, out);
}

// Round 16
// 62.024 us; speedup vs baseline: 2.1470x; 1.0228x over previous
//
#include <hip/hip_runtime.h>

#define BB 4
#define CIN 256
#define COUT 256
#define HH 64
#define WW 64
#define KK 9
#define OC2 18
#define KTOT (CIN * KK)        // 2304 = 72 x 32-k steps = 18 x 128-k stages

typedef __attribute__((ext_vector_type(8))) _Float16 h8;
typedef __attribute__((ext_vector_type(4))) float f32x4;

static __device__ __forceinline__ h8 splat_pk(unsigned pk) {
    union { unsigned u[4]; h8 h; } s;
    s.u[0] = pk; s.u[1] = pk; s.u[2] = pk; s.u[3] = pk;
    return s.h;
}

// ---------------------------------------------------------------------------
// Kernel 1: prework, 512 blocks x 512 thr.
//   - transpose x -> xT pixel-major f16 (2 chunks per block)
//   - pack dcn_w -> bp (144 words/block)
//   - pack offset_w -> bow (18 words/block, oc padded 18->32)
// ---------------------------------------------------------------------------
__global__ __launch_bounds__(512) void prework_kernel(
    const float* __restrict__ x, const float* __restrict__ ow,
    const float* __restrict__ dw,
    _Float16* __restrict__ xT, _Float16* __restrict__ bp,
    _Float16* __restrict__ bow)
{
    __shared__ float tile[2][64][65];     // 33.3 KB

    const int tid = threadIdx.x;
    const int half = tid >> 8, t = tid & 255;
    const int chunk = (blockIdx.x << 1) + half;       // 0..1023
    const int tb = chunk >> 8, ty = (chunk >> 2) & 63, tc0 = (chunk & 3) * 64;

#pragma unroll
    for (int r = 0; r < 16; ++r) {
        int idx = r * 256 + t;
        int c = idx >> 6, w = idx & 63;
        tile[half][c][w] = x[(((size_t)(tb * CIN + tc0 + c)) << 12) + (ty << 6) + w];
    }
    __syncthreads();
    const int px = t >> 2;
#pragma unroll
    for (int h2 = 0; h2 < 2; ++h2) {
        int cc = (t & 3) + h2 * 4;
        union { _Float16 h[8]; uint4 q; } u;
#pragma unroll
        for (int j = 0; j < 8; ++j) u.h[j] = (_Float16)tile[half][cc * 8 + j][px];
        size_t el = (((size_t)(tb << 12)) + (ty << 6) + px) * 256 + tc0 + cc * 8;
        *(uint4*)&xT[el] = u.q;
    }

    // pack dcn_w: word wid = (T*16 + cotile)*64 + lane2 (T = 32-k step)
    if (tid < 144) {
        int wid = blockIdx.x * 144 + tid;             // 73728 total
        int T = wid >> 10;
        int r = wid & 1023;
        int cotile = r >> 6, lane2 = r & 63;
        int co = cotile * 16 + (lane2 & 15);
        int kbase = T * 32 + ((lane2 >> 4) & 3) * 8;
        union { _Float16 h[8]; uint4 q; } u;
#pragma unroll
        for (int j = 0; j < 8; ++j) {
            int k = kbase + j;
            int c = k & 255, kk = k >> 8;
            u.h[j] = (_Float16)dw[co * KTOT + c * KK + kk];
        }
        *(uint4*)&bp[(size_t)wid * 8] = u.q;
    }
    // pack offset_w: wid = (T*2+nj)*64+lane2
    if (tid >= 256 && tid < 274) {
        int wid = blockIdx.x * 18 + (tid - 256);      // 9216 total
        int T = wid >> 7;
        int r = wid & 127;
        int lane2 = r & 63;
        int oc = ((r >> 6) << 4) + (lane2 & 15);
        int kbase = T * 32 + ((lane2 >> 4) & 3) * 8;
        union { _Float16 h[8]; uint4 q; } u;
#pragma unroll
        for (int j = 0; j < 8; ++j) {
            int k = kbase + j;
            int c = k & 255, kk = k >> 8;
            u.h[j] = (oc < OC2) ? (_Float16)ow[oc * KTOT + c * KK + kk] : (_Float16)0.f;
        }
        *(uint4*)&bow[(size_t)wid * 8] = u.q;
    }
}

// ---------------------------------------------------------------------------
// Kernel 2: fused {offset-conv + bilinear-gather + MFMA implicit GEMM}, v16.
// 512 blocks (32px x 256co) = 2/CU, 512 thr = 8 waves.
// Phase 0: in-block offset conv, K split across 8 waves, 2-deep register
//   pipeline; partials to stride-33 LDS scratch (conflict-free).
// Phase 1: bilinear table (fixed-order wave sum -> deterministic).
// Phase 2: 18-stage main loop (identical to R12/R13): A gathered once per
//   block to XOR-layout LDS, B global->regs per-wave, 1-stage prefetch.
// ---------------------------------------------------------------------------
__global__ __launch_bounds__(512, 4) void dcn_mfma_kernel(
    const _Float16* __restrict__ xT, const _Float16* __restrict__ bow,
    const float* __restrict__ ob, const _Float16* __restrict__ bp,
    const float* __restrict__ db, float* __restrict__ out)
{
    // region0 [0,33792): oscr f32[8][32][33] / Asl[2][4096] f16 (16 KB)
    // [33792,38400): twp   [38400,43008): tih
    __shared__ __align__(16) char smem[33792 + 4608 + 4608];
    _Float16 (*Asl)[4096] = (_Float16(*)[4096])smem;
    float* oscr = (float*)smem;
    uint2* twp = (uint2*)(smem + 33792);
    uint2* tih = (uint2*)(smem + 33792 + 4608);

    int P = blockIdx.x;
    int L = (P & 7) * 64 + (P >> 3);      // XCD swizzle (512 % 8 == 0)
    const int b = L >> 7;
    const int rowbase = (L & 127) * 32;   // 32-px m-tile

    const int tid = threadIdx.x;
    const int lane = tid & 63;
    const int wn = tid >> 6;              // 0..7 = co slice / K-slice
    const int colg = lane & 15, kg = lane >> 4;

    const char* xbyte = (const char*)(xT + ((size_t)b << 20));  // uniform

    // ================= Phase 0: in-block offset conv (2-deep pipeline) ====
    {
        f32x4 oacc[2][2];
#pragma unroll
        for (int mi = 0; mi < 2; ++mi)
#pragma unroll
            for (int nj = 0; nj < 2; ++nj) { f32x4 z = {0.f,0.f,0.f,0.f}; oacc[mi][nj] = z; }

        const int T0 = wn * 9;            // this wave's K-slice

        h8 aA[2], aB[2];
        uint4 bwA[2], bwB[2];

        auto OLOAD = [&](int T, h8* a, uint4* bw) {
            int kk = T >> 3;
            int ky = kk / 3, kx = kk - 3 * (kk / 3);
            int cgo = ((T & 7) << 2) + kg;
#pragma unroll
            for (int mi = 0; mi < 2; ++mi) {
                int pxl = rowbase + mi * 16 + colg;
                int yy = (pxl >> 6) + ky - 1, xx = (pxl & 63) + kx - 1;
                h8 v = {0,0,0,0,0,0,0,0};
                if ((unsigned)yy < HH && (unsigned)xx < WW)
                    v = *(const h8*)(xbyte + ((((yy << 6) + xx) << 9) + (cgo << 4)));
                a[mi] = v;
            }
#pragma unroll
            for (int nj = 0; nj < 2; ++nj)
                bw[nj] = *(const uint4*)&bow[(size_t)(((T << 1) + nj) * 64 + lane) * 8];
        };
        auto OMFMA = [&](const h8* a, const uint4* bw) {
            union { uint4 q; h8 h; } b0, b1;
            b0.q = bw[0]; b1.q = bw[1];
#pragma unroll
            for (int mi = 0; mi < 2; ++mi) {
                oacc[mi][0] = __builtin_amdgcn_mfma_f32_16x16x32_f16(a[mi], b0.h, oacc[mi][0], 0, 0, 0);
                oacc[mi][1] = __builtin_amdgcn_mfma_f32_16x16x32_f16(a[mi], b1.h, oacc[mi][1], 0, 0, 0);
            }
        };

        OLOAD(T0, aA, bwA);
#pragma unroll
        for (int i = 0; i < 9; ++i) {     // full unroll: (i&1) compile-time
            if (i + 1 < 9) {
                if (i & 1) OLOAD(T0 + i + 1, aA, bwA);
                else       OLOAD(T0 + i + 1, aB, bwB);
            }
            if (i & 1) OMFMA(aB, bwB);
            else       OMFMA(aA, bwA);
        }

        // partials -> scratch [w][px(32)][33-padded oc]
#pragma unroll
        for (int mi = 0; mi < 2; ++mi)
#pragma unroll
            for (int nj = 0; nj < 2; ++nj) {
                int px0 = mi * 16 + kg * 4;
                int oc = nj * 16 + colg;
#pragma unroll
                for (int r = 0; r < 4; ++r)
                    oscr[(wn * 32 + px0 + r) * 33 + oc] = oacc[mi][nj][r];
            }
    }
    __syncthreads();

    // ================= Phase 1: bilinear table (32 px x 9 taps) ==========
    if (tid < 288) {
        int e = tid;
        int p = e / 9, kk = e - (e / 9) * 9;
        float dy = ob[2 * kk], dx = ob[2 * kk + 1];
#pragma unroll
        for (int w2 = 0; w2 < 8; ++w2) {          // fixed order: deterministic
            dy += oscr[(w2 * 32 + p) * 33 + 2 * kk];
            dx += oscr[(w2 * 32 + p) * 33 + 2 * kk + 1];
        }
        int pxl = rowbase + p;
        int y = pxl >> 6, xx = pxl & 63;
        int ky = kk / 3, kx = kk - 3 * (kk / 3);
        float sy = (float)(y - 1 + ky) + dy;
        float sx = (float)(xx - 1 + kx) + dx;
        float fy = floorf(sy), fx = floorf(sx);
        int y0 = (int)fy, x0 = (int)fx;
        float wy1 = sy - fy, wx1 = sx - fx;
        float wy0 = 1.f - wy1, wx0 = 1.f - wx1;
        bool vy0 = (unsigned)y0 < HH, vy1 = (unsigned)(y0 + 1) < HH;
        bool vx0 = (unsigned)x0 < WW, vx1 = (unsigned)(x0 + 1) < WW;
        _Float16 w00 = (_Float16)((vy0 && vx0) ? wy0 * wx0 : 0.f);
        _Float16 w01 = (_Float16)((vy0 && vx1) ? wy0 * wx1 : 0.f);
        _Float16 w10 = (_Float16)((vy1 && vx0) ? wy1 * wx0 : 0.f);
        _Float16 w11 = (_Float16)((vy1 && vx1) ? wy1 * wx1 : 0.f);
        union { _Float16 h[2]; unsigned u; } pk2;
        uint2 W;
        pk2.h[0] = w00; pk2.h[1] = w01; W.x = pk2.u;
        pk2.h[0] = w10; pk2.h[1] = w11; W.y = pk2.u;
        twp[e] = W;
        int y0c = min(max(y0, 0), HH - 1), y1c = min(max(y0 + 1, 0), HH - 1);
        int x0c = min(max(x0, 0), WW - 1), x1c = min(max(x0 + 1, 0), WW - 1);
        unsigned i00 = (unsigned)((y0c << 6) + x0c);
        unsigned i01 = (unsigned)((y0c << 6) + x1c);
        unsigned i10 = (unsigned)((y1c << 6) + x0c);
        unsigned i11 = (unsigned)((y1c << 6) + x1c);
        tih[e] = make_uint2(i00 | (i01 << 16), i10 | (i11 << 16));
    }
    __syncthreads();   // tables visible; oscr reads done (Asl may now alias)

    // ================= Phase 2: main implicit GEMM (R12/R13 core) ========
    const int g_px = tid >> 4;            // 0..31 px within tile
    const int g_cg = tid & 15;            // 8-ch chunk within 128-k stage
    const int g_ebase = g_px * 9;
    const int g_w0 = g_cg * 32 + (g_px ^ (g_cg & 7));   // XOR layout

    auto AGLOAD = [&](int st, h8* C) {
        uint2 ij = tih[g_ebase + (st >> 1)];
        unsigned chb = (unsigned)((st & 1) * 256 + g_cg * 16);
        C[0] = *(const h8*)(xbyte + (((ij.x & 0xFFFFu) << 9) + chb));
        C[1] = *(const h8*)(xbyte + (((ij.x >> 16)     << 9) + chb));
        C[2] = *(const h8*)(xbyte + (((ij.y & 0xFFFFu) << 9) + chb));
        C[3] = *(const h8*)(xbyte + (((ij.y >> 16)     << 9) + chb));
    };
    auto GCONSUME = [&](int st, int buf, const h8* C) {
        uint2 w = twp[g_ebase + (st >> 1)];
        unsigned w00 = (w.x & 0xFFFFu) * 0x10001u;
        unsigned w01 = (w.x >> 16)     * 0x10001u;
        unsigned w10 = (w.y & 0xFFFFu) * 0x10001u;
        unsigned w11 = (w.y >> 16)     * 0x10001u;
        h8 v = C[0] * splat_pk(w00);
        v += C[1] * splat_pk(w01);
        v += C[2] * splat_pk(w10);
        v += C[3] * splat_pk(w11);
        *(h8*)&Asl[buf][g_w0 * 8] = v;
    };
    auto BLOAD = [&](int st, uint4* br) {
#pragma unroll
        for (int ks = 0; ks < 4; ++ks)
#pragma unroll
            for (int nj = 0; nj < 2; ++nj) {
                size_t word = ((size_t)((st * 4 + ks) * 16 + wn * 2 + nj)) * 64 + lane;
                br[ks * 2 + nj] = *(const uint4*)&bp[word * 8];
            }
    };

    f32x4 acc[2][2];
#pragma unroll
    for (int mi = 0; mi < 2; ++mi)
#pragma unroll
        for (int nj = 0; nj < 2; ++nj) { f32x4 z = {0.f,0.f,0.f,0.f}; acc[mi][nj] = z; }

    auto MFMA16 = [&](int buf, uint4* br) {
        __builtin_amdgcn_s_setprio(1);
#pragma unroll
        for (int ks = 0; ks < 4; ++ks) {
            const int cg = ks * 4 + kg;
            union { uint4 q; h8 h; } b0, b1;
            b0.q = br[ks * 2]; b1.q = br[ks * 2 + 1];
#pragma unroll
            for (int mi = 0; mi < 2; ++mi) {
                int w = cg * 32 + ((mi * 16 + colg) ^ (cg & 7));
                h8 a = *(const h8*)&Asl[buf][w * 8];
                acc[mi][0] = __builtin_amdgcn_mfma_f32_16x16x32_f16(a, b0.h, acc[mi][0], 0, 0, 0);
                acc[mi][1] = __builtin_amdgcn_mfma_f32_16x16x32_f16(a, b1.h, acc[mi][1], 0, 0, 0);
            }
        }
        __builtin_amdgcn_s_setprio(0);
    };

    h8 C[4];
    uint4 breg[8], bnext[8];

    AGLOAD(0, C);
    BLOAD(0, breg);
    GCONSUME(0, 0, C);
    __syncthreads();

    for (int s = 0; s < 18; ++s) {
        const int cur = s & 1;
        if (s + 1 < 18) {
            AGLOAD(s + 1, C);             // corner prefetch in flight over MFMAs
            BLOAD(s + 1, bnext);          // B prefetch in flight
        }
        MFMA16(cur, breg);
        if (s + 1 < 18) GCONSUME(s + 1, cur ^ 1, C);
        __syncthreads();
#pragma unroll
        for (int i = 0; i < 8; ++i) breg[i] = bnext[i];
    }

    // ---- epilogue: col=lane&15 -> co, row=(lane>>4)*4+reg -> px ----
#pragma unroll
    for (int nj = 0; nj < 2; ++nj) {
        const int co = wn * 32 + nj * 16 + colg;
        const float bv = db[co];
        float* op = out + ((size_t)(b * COUT + co) << 12) + rowbase + kg * 4;
#pragma unroll
        for (int mi = 0; mi < 2; ++mi) {
            float4 o;
            o.x = acc[mi][nj][0] + bv;
            o.y = acc[mi][nj][1] + bv;
            o.z = acc[mi][nj][2] + bv;
            o.w = acc[mi][nj][3] + bv;
            *(float4*)&op[mi * 16] = o;
        }
    }
}

// ---------------------------------------------------------------------------
extern "C" void kernel_launch(void* const* d_in, const int* in_sizes, int n_in,
                              void* d_out, int out_size, void* d_ws, size_t ws_size,
                              hipStream_t stream)
{
    const float* x  = (const float*)d_in[0];
    const float* ow = (const float*)d_in[1];
    const float* ob = (const float*)d_in[2];
    const float* dw = (const float*)d_in[3];
    const float* db = (const float*)d_in[4];
    float* out = (float*)d_out;

    // ws layout (bytes): bp f16 1179648 | bow f16 147456 | xT f16 8388608
    char* wsp = (char*)d_ws;
    _Float16*  bp  = (_Float16*)wsp;
    _Float16*  bow = (_Float16*)(wsp + 1179648);
    _Float16*  xT  = (_Float16*)(wsp + 1327104);

    hipLaunchKernelGGL(prework_kernel,  dim3(512), dim3(512), 0, stream, x, ow, dw, xT, bp, bow);
    hipLaunchKernelGGL(dcn_mfma_kernel, dim3(512), dim3(512), 0, stream, xT, bow, ob, bp, db, out);
}